// Round 1
// baseline (17915.263 us; speedup 1.0000x reference)
//
#include <hip/hip_runtime.h>
#include <math.h>

#define INF __builtin_inff()

// ---------------- workspace layout (float offsets) ----------------
// xg      : 0        (1024 x 2048)
// h_seq   : 2097152  (257 x 4 x 512)   h_seq[t][b][u], t=0 is h0=0
// q       : 2623488  (1024 x 128)
// invn    : 2754560  (100000)
// mem_pre : 2854560  (1024 x 128)
// mem_cmb : 2985632  (1024 x 128)
// pvals   : 3116704  (32 x 1024 x 3)
// pidx    : 3215008  (32 x 1024 x 3)  int
// cnt     : 3313312  (256 x 4)        uint barrier counters
// total ~ 12.7 MB

__device__ __forceinline__ void ins3(float& v0, int& i0, float& v1, int& i1,
                                     float& v2, int& i2, float nv, int ni) {
  // keep (v0,i0) >= (v1,i1) >= (v2,i2); ties -> lower index wins (jax top_k)
  if (nv > v2 || (nv == v2 && ni < i2)) {
    v2 = nv; i2 = ni;
    if (v2 > v1 || (v2 == v1 && i2 < i1)) {
      float tv = v1; int ti = i1; v1 = v2; i1 = i2; v2 = tv; i2 = ti;
      if (v1 > v0 || (v1 == v0 && i1 < i0)) {
        float sv = v0; int si = i0; v0 = v1; i0 = i1; v1 = sv; i1 = si;
      }
    }
  }
}

__global__ void init_k(float* __restrict__ h_seq, unsigned* __restrict__ cnt) {
  int t = blockIdx.x * 256 + threadIdx.x;   // grid 8 x 256
  if (t < 2048) h_seq[t] = 0.f;             // h_seq[0][*][*] = 0
  if (t < 1024) cnt[t] = 0u;                // barrier counters (ws is poisoned!)
}

// ---------------- generic tiled GEMM: C(MxN) = A(MxK) @ B(NxK)^T + bias ----
// AMODE 0: A plain row-major.  AMODE 1: A row r=(b*256+s) -> h_seq[(s+1)*4+b].
// AMODE 2: concat [h | A2(1024x128)], K=640.
template<int AMODE>
__global__ __launch_bounds__(256) void gemm_k(
    const float* __restrict__ A, const float* __restrict__ A2,
    const float* __restrict__ Bw, const float* __restrict__ b1,
    const float* __restrict__ b2, float* __restrict__ C,
    int M, int N, int K) {
  __shared__ float4 As4[64][16];
  __shared__ float4 Bs4[64][16];
  const int t = threadIdx.x;
  const int tx = t & 15, ty = t >> 4;
  const int brow = blockIdx.x * 64, bcol = blockIdx.y * 64;
  const int srow = t >> 2, scb = t & 3;
  float acc[4][4] = {};
  for (int kt = 0; kt < K; kt += 64) {
#pragma unroll
    for (int u = 0; u < 4; ++u) {
      int c = scb + 4 * u;           // float4 column 0..15
      int gk = kt + c * 4;
      int gr = brow + srow;
      const float* ap;
      if (AMODE == 0) {
        ap = A + (size_t)gr * K + gk;
      } else {
        int b = gr >> 8, s = gr & 255;
        const float* hrow = A + ((size_t)(s + 1) * 4 + b) * 512;
        if (AMODE == 1) ap = hrow + gk;
        else ap = (gk < 512) ? (hrow + gk) : (A2 + (size_t)gr * 128 + (gk - 512));
      }
      As4[srow][c ^ (srow & 15)] = *(const float4*)ap;
      Bs4[srow][c ^ (srow & 15)] = *(const float4*)(Bw + (size_t)(bcol + srow) * K + gk);
    }
    __syncthreads();
#pragma unroll
    for (int d4 = 0; d4 < 16; ++d4) {
      float4 av[4], bv[4];
#pragma unroll
      for (int i = 0; i < 4; ++i) av[i] = As4[ty * 4 + i][d4 ^ ((ty * 4 + i) & 15)];
#pragma unroll
      for (int j = 0; j < 4; ++j) bv[j] = Bs4[tx * 4 + j][d4 ^ ((tx * 4 + j) & 15)];
#pragma unroll
      for (int i = 0; i < 4; ++i)
#pragma unroll
        for (int j = 0; j < 4; ++j)
          acc[i][j] += av[i].x * bv[j].x + av[i].y * bv[j].y +
                       av[i].z * bv[j].z + av[i].w * bv[j].w;
    }
    __syncthreads();
  }
#pragma unroll
  for (int i = 0; i < 4; ++i) {
    int r = brow + ty * 4 + i;
#pragma unroll
    for (int j = 0; j < 4; ++j) {
      int n = bcol + tx * 4 + j;
      float bias = b1[n];
      if (b2) bias += b2[n];
      C[(size_t)r * N + n] = acc[i][j] + bias;
    }
  }
}

// ---------------- LSTM recurrence: persistent, per-step device barrier -----
// 64 blocks x 512 threads. block bid: batch=bid>>4, owns 32 hidden units.
// W_hh slice lives in REGISTERS (loaded once). h broadcast via h_seq + counter
// barrier (agent scope). All 64 blocks trivially co-resident (2.3KB LDS).
__global__ __launch_bounds__(512, 1) void lstm_k(
    const float* __restrict__ xg, const float* __restrict__ W_hh,
    float* __restrict__ h_seq, unsigned* __restrict__ cnt) {
  const int bid = blockIdx.x;
  const int batch = bid >> 4;          // 16 blocks per batch
  const int ub = bid & 15;
  const int t = threadIdx.x;           // 512
  const int uu = t >> 4;               // 0..31 local unit
  const int li = t & 15;               // 16 lanes per unit, 32 d-elems each
  const int unit = ub * 32 + uu;
  __shared__ float h_lds[16 * 36];     // swizzled: idx(d) = (d>>5)*36 + (d&31)

  float w[4][32];                      // W_hh[g*512+unit][li*32 .. +32)
#pragma unroll
  for (int g = 0; g < 4; ++g) {
    const float* wr = W_hh + (size_t)(g * 512 + unit) * 512 + li * 32;
#pragma unroll
    for (int j = 0; j < 32; j += 4) {
      float4 v = *(const float4*)(wr + j);
      w[g][j] = v.x; w[g][j + 1] = v.y; w[g][j + 2] = v.z; w[g][j + 3] = v.w;
    }
  }
  float c = 0.f;
  float xgv[4];
#pragma unroll
  for (int g = 0; g < 4; ++g)
    xgv[g] = xg[(size_t)(batch * 256) * 2048 + g * 512 + unit];

  for (int step = 0; step < 256; ++step) {
    // gather h(step) -> LDS (all 512 values of this batch)
    {
      float hv = h_seq[(size_t)(step * 4 + batch) * 512 + t];
      h_lds[(t >> 5) * 36 + (t & 31)] = hv;
    }
    __syncthreads();
    float a0 = 0, a1 = 0, a2 = 0, a3 = 0;
#pragma unroll
    for (int j = 0; j < 32; j += 4) {
      float4 hv = *(const float4*)(&h_lds[li * 36 + j]);
      a0 += w[0][j] * hv.x + w[0][j + 1] * hv.y + w[0][j + 2] * hv.z + w[0][j + 3] * hv.w;
      a1 += w[1][j] * hv.x + w[1][j + 1] * hv.y + w[1][j + 2] * hv.z + w[1][j + 3] * hv.w;
      a2 += w[2][j] * hv.x + w[2][j + 1] * hv.y + w[2][j + 2] * hv.z + w[2][j + 3] * hv.w;
      a3 += w[3][j] * hv.x + w[3][j + 1] * hv.y + w[3][j + 2] * hv.z + w[3][j + 3] * hv.w;
    }
#pragma unroll
    for (int m = 1; m < 16; m <<= 1) {   // reduce across the 16 lanes of a unit
      a0 += __shfl_xor(a0, m, 64); a1 += __shfl_xor(a1, m, 64);
      a2 += __shfl_xor(a2, m, 64); a3 += __shfl_xor(a3, m, 64);
    }
    float gi = a0 + xgv[0], gf = a1 + xgv[1], gg = a2 + xgv[2], go = a3 + xgv[3];
    float i_ = 1.f / (1.f + expf(-gi));
    float f_ = 1.f / (1.f + expf(-gf));
    float g_ = tanhf(gg);
    float o_ = 1.f / (1.f + expf(-go));
    c = f_ * c + i_ * g_;
    float h = o_ * tanhf(c);
    if (li == 0) h_seq[(size_t)((step + 1) * 4 + batch) * 512 + unit] = h;
    if (step < 255) {
#pragma unroll
      for (int g = 0; g < 4; ++g)        // prefetch next xg (hides L2 latency)
        xgv[g] = xg[(size_t)(batch * 256 + step + 1) * 2048 + g * 512 + unit];
      __syncthreads();                   // drains vmcnt: h stores complete
      if (t == 0) {
        unsigned* pc = cnt + (step * 4 + batch);
        __hip_atomic_fetch_add(pc, 1u, __ATOMIC_ACQ_REL, __HIP_MEMORY_SCOPE_AGENT);
        while (__hip_atomic_load(pc, __ATOMIC_ACQUIRE, __HIP_MEMORY_SCOPE_AGENT) < 16u)
          __builtin_amdgcn_s_sleep(2);
      }
      __syncthreads();
    }
  }
}

// ---------------- q row-normalize (F.normalize, eps=1e-12) -----------------
__global__ __launch_bounds__(256) void qnorm_k(float* __restrict__ q) {
  int wv = threadIdx.x >> 6, lane = threadIdx.x & 63;
  int r = blockIdx.x * 4 + wv;
  float2 v = *(float2*)(q + (size_t)r * 128 + lane * 2);
  float ss = v.x * v.x + v.y * v.y;
#pragma unroll
  for (int m = 1; m < 64; m <<= 1) ss += __shfl_xor(ss, m, 64);
  float inv = 1.f / fmaxf(sqrtf(ss), 1e-12f);
  v.x *= inv; v.y *= inv;
  *(float2*)(q + (size_t)r * 128 + lane * 2) = v;
}

// ---------------- key inverse norms ----------------------------------------
__global__ __launch_bounds__(256) void invnorm_k(const float* __restrict__ keys,
                                                 float* __restrict__ invn) {
  int wv = threadIdx.x >> 6, lane = threadIdx.x & 63;
  int r = blockIdx.x * 4 + wv;   // grid 25000 -> exactly 100000 rows
  float2 v = *(const float2*)(keys + (size_t)r * 128 + lane * 2);
  float ss = v.x * v.x + v.y * v.y;
#pragma unroll
  for (int m = 1; m < 64; m <<= 1) ss += __shfl_xor(ss, m, 64);
  if (lane == 0) invn[r] = 1.f / fmaxf(sqrtf(ss), 1e-12f);
}

// ---------------- fused sims + per-chunk top-3 ------------------------------
// grid (16 qtiles, 32 chunks). 64q x 64k LDS tiles, XOR-swizzled float4 layout
// (2-way max bank conflict), 4x4 register micro-tile, fp32 throughout.
__global__ __launch_bounds__(256) void sims_topk(
    const float* __restrict__ q, const float* __restrict__ keys,
    const float* __restrict__ invn, float* __restrict__ pvals,
    int* __restrict__ pidx) {
  const int qt = blockIdx.x;
  const int ch = blockIdx.y;
  const int CH = 3125;
  const int kbeg = ch * CH, klim = kbeg + CH;
  const int t = threadIdx.x, tx = t & 15, ty = t >> 4;
  __shared__ float4 qs4[64][32];
  __shared__ float4 ks4[64][32];
  const int srow = t >> 2, scb = t & 3;
#pragma unroll
  for (int u = 0; u < 8; ++u) {
    int cc = scb + 4 * u;
    qs4[srow][cc ^ (srow & 31)] =
        *(const float4*)(q + (size_t)(qt * 64 + srow) * 128 + cc * 4);
  }
  float tv0[4], tv1[4], tv2[4]; int ti0[4], ti1[4], ti2[4];
#pragma unroll
  for (int i = 0; i < 4; ++i) {
    tv0[i] = tv1[i] = tv2[i] = -INF;
    ti0[i] = ti1[i] = ti2[i] = 0x7fffffff;
  }
  for (int k0 = kbeg; k0 < klim; k0 += 64) {
#pragma unroll
    for (int u = 0; u < 8; ++u) {
      int cc = scb + 4 * u;
      int kk = k0 + srow;
      float4 v = make_float4(0.f, 0.f, 0.f, 0.f);
      if (kk < klim) v = *(const float4*)(keys + (size_t)kk * 128 + cc * 4);
      ks4[srow][cc ^ (srow & 31)] = v;
    }
    float invr[4];
#pragma unroll
    for (int j = 0; j < 4; ++j) {
      int gk = k0 + tx * 4 + j;
      invr[j] = (gk < klim) ? invn[gk] : 0.f;
    }
    __syncthreads();
    float acc[4][4] = {};
#pragma unroll
    for (int d4 = 0; d4 < 32; ++d4) {
      float4 av[4], bv[4];
#pragma unroll
      for (int i = 0; i < 4; ++i) av[i] = qs4[ty * 4 + i][d4 ^ ((ty * 4 + i) & 31)];
#pragma unroll
      for (int j = 0; j < 4; ++j) bv[j] = ks4[tx * 4 + j][d4 ^ ((tx * 4 + j) & 31)];
#pragma unroll
      for (int i = 0; i < 4; ++i)
#pragma unroll
        for (int j = 0; j < 4; ++j)
          acc[i][j] += av[i].x * bv[j].x + av[i].y * bv[j].y +
                       av[i].z * bv[j].z + av[i].w * bv[j].w;
    }
#pragma unroll
    for (int i = 0; i < 4; ++i)
#pragma unroll
      for (int j = 0; j < 4; ++j) {
        int gk = k0 + tx * 4 + j;
        float sim = (gk < klim) ? acc[i][j] * invr[j] : -INF;
        ins3(tv0[i], ti0[i], tv1[i], ti1[i], tv2[i], ti2[i], sim, gk);
      }
    __syncthreads();
  }
  // merge the 16 key-column threads per query via LDS (reuse qs4 storage)
  float* ms = (float*)qs4;
#pragma unroll
  for (int i = 0; i < 4; ++i) {
    int base = ((ty * 4 + i) * 16 + tx) * 6;
    ms[base + 0] = tv0[i]; ms[base + 1] = __int_as_float(ti0[i]);
    ms[base + 2] = tv1[i]; ms[base + 3] = __int_as_float(ti1[i]);
    ms[base + 4] = tv2[i]; ms[base + 5] = __int_as_float(ti2[i]);
  }
  __syncthreads();
  if (t < 64) {
    float v0 = -INF, v1 = -INF, v2 = -INF;
    int i0 = 0x7fffffff, i1 = i0, i2 = i0;
    for (int xx = 0; xx < 16; ++xx) {
      int base = (t * 16 + xx) * 6;
#pragma unroll
      for (int e = 0; e < 3; ++e)
        ins3(v0, i0, v1, i1, v2, i2, ms[base + e * 2],
             __float_as_int(ms[base + e * 2 + 1]));
    }
    size_t ob = ((size_t)ch * 1024 + qt * 64 + t) * 3;
    pvals[ob + 0] = v0; pvals[ob + 1] = v1; pvals[ob + 2] = v2;
    pidx[ob + 0] = i0; pidx[ob + 1] = i1; pidx[ob + 2] = i2;
  }
}

// ---------------- final merge + gather + attention + weighted sum ----------
__global__ __launch_bounds__(256) void attn_k(
    const float* __restrict__ pvals, const int* __restrict__ pidx,
    const float* __restrict__ mvals, const float* __restrict__ Wa,
    const float* __restrict__ ba, float* __restrict__ mem_pre) {
  int wv = threadIdx.x >> 6, lane = threadIdx.x & 63;
  int qr = blockIdx.x * 4 + wv;    // grid 256 -> 1024 queries, wave per query
  float v0 = -INF, v1 = -INF, v2 = -INF;
  int i0 = 0x7fffffff, i1 = i0, i2 = i0;
  for (int ch = 0; ch < 32; ++ch) {
    size_t base = ((size_t)ch * 1024 + qr) * 3;
#pragma unroll
    for (int e = 0; e < 3; ++e)
      ins3(v0, i0, v1, i1, v2, i2, pvals[base + e], pidx[base + e]);
  }
  int d = lane * 2;
  float r00 = mvals[(size_t)i0 * 128 + d], r01 = mvals[(size_t)i0 * 128 + d + 1];
  float r10 = mvals[(size_t)i1 * 128 + d], r11 = mvals[(size_t)i1 * 128 + d + 1];
  float r20 = mvals[(size_t)i2 * 128 + d], r21 = mvals[(size_t)i2 * 128 + d + 1];
  float wa0 = Wa[d], wa1 = Wa[d + 1];
  float p0 = wa0 * r00 + wa1 * r01;
  float p1 = wa0 * r10 + wa1 * r11;
  float p2 = wa0 * r20 + wa1 * r21;
#pragma unroll
  for (int m = 1; m < 64; m <<= 1) {
    p0 += __shfl_xor(p0, m, 64);
    p1 += __shfl_xor(p1, m, 64);
    p2 += __shfl_xor(p2, m, 64);
  }
  float bav = ba[0];
  float l0 = p0 + bav, l1 = p1 + bav, l2 = p2 + bav;
  float mx = fmaxf(l0, fmaxf(l1, l2));
  float e0 = expf(l0 - mx), e1 = expf(l1 - mx), e2 = expf(l2 - mx);
  float s = e0 + e1 + e2;
  float a0 = e0 / s, a1 = e1 / s, a2 = e2 / s;
  mem_pre[(size_t)qr * 128 + d]     = a0 * r00 + a1 * r10 + a2 * r20;
  mem_pre[(size_t)qr * 128 + d + 1] = a0 * r01 + a1 * r11 + a2 * r21;
}

// ---------------------------------------------------------------------------
extern "C" void kernel_launch(void* const* d_in, const int* in_sizes, int n_in,
                              void* d_out, int out_size, void* d_ws, size_t ws_size,
                              hipStream_t stream) {
  (void)in_sizes; (void)n_in; (void)out_size; (void)ws_size;
  const float* x    = (const float*)d_in[0];
  const float* W_ih = (const float*)d_in[1];
  const float* W_hh = (const float*)d_in[2];
  const float* b_ih = (const float*)d_in[3];
  const float* b_hh = (const float*)d_in[4];
  const float* Wq   = (const float*)d_in[5];
  const float* bq   = (const float*)d_in[6];
  const float* Wa   = (const float*)d_in[7];
  const float* ba   = (const float*)d_in[8];
  const float* Wc   = (const float*)d_in[9];
  const float* bc   = (const float*)d_in[10];
  const float* Wo   = (const float*)d_in[11];
  const float* bo   = (const float*)d_in[12];
  const float* keys = (const float*)d_in[13];
  const float* vals = (const float*)d_in[14];

  float* ws      = (float*)d_ws;
  float* xg      = ws + 0;
  float* h_seq   = ws + 2097152;
  float* qbuf    = ws + 2623488;
  float* invn    = ws + 2754560;
  float* mem_pre = ws + 2854560;
  float* mem_cmb = ws + 2985632;
  float* pvals   = ws + 3116704;
  int*   pidx    = (int*)(ws + 3215008);
  unsigned* cnt  = (unsigned*)(ws + 3313312);

  init_k<<<8, 256, 0, stream>>>(h_seq, cnt);
  // xg = x @ W_ih^T + (b_ih + b_hh)
  gemm_k<0><<<dim3(16, 32), 256, 0, stream>>>(x, nullptr, W_ih, b_ih, b_hh, xg,
                                              1024, 2048, 256);
  invnorm_k<<<25000, 256, 0, stream>>>(keys, invn);
  lstm_k<<<64, 512, 0, stream>>>(xg, W_hh, h_seq, cnt);
  // q = h @ Wq^T + bq, then row-normalize
  gemm_k<1><<<dim3(16, 2), 256, 0, stream>>>(h_seq, nullptr, Wq, bq, nullptr,
                                             qbuf, 1024, 128, 512);
  qnorm_k<<<256, 256, 0, stream>>>(qbuf);
  sims_topk<<<dim3(16, 32), 256, 0, stream>>>(qbuf, keys, invn, pvals, pidx);
  attn_k<<<256, 256, 0, stream>>>(pvals, pidx, vals, Wa, ba, mem_pre);
  // mem = mem_pre @ Wc^T + bc
  gemm_k<0><<<dim3(16, 2), 256, 0, stream>>>(mem_pre, nullptr, Wc, bc, nullptr,
                                             mem_cmb, 1024, 128, 128);
  // out = [h | mem] @ Wo^T + bo
  gemm_k<2><<<dim3(16, 4), 256, 0, stream>>>(h_seq, mem_cmb, Wo, bo, nullptr,
                                             (float*)d_out, 1024, 256, 640);
}

// Round 2
// 2251.283 us; speedup vs baseline: 7.9578x; 7.9578x over previous
//
#include <hip/hip_runtime.h>
#include <math.h>

#define INF __builtin_inff()

// ---------------- workspace layout (float offsets) ----------------
// xg      : 0        (1024 x 2048)
// h_seq   : 2097152  (257 x 4 x 512)   h_seq[t][b][u], t=0 is h0=0
// q       : 2623488  (1024 x 128)
// invn    : 2754560  (100000)
// mem_pre : 2854560  (1024 x 128)
// mem_cmb : 2985632  (1024 x 128)
// pvals   : 3116704  (32 x 1024 x 3)
// pidx    : 3215008  (32 x 1024 x 3)  int
// cnt     : 3313312  (256 x 4)        uint barrier counters

// branchless ordered top-3 insert; ties -> lower index wins (jax top_k)
__device__ __forceinline__ void ins3b(float& v0, int& i0, float& v1, int& i1,
                                      float& v2, int& i2, float nv, int ni) {
  bool b0 = (nv > v0) || (nv == v0 && ni < i0);
  bool b1 = (nv > v1) || (nv == v1 && ni < i1);
  bool b2 = (nv > v2) || (nv == v2 && ni < i2);
  v2 = b1 ? v1 : (b2 ? nv : v2);
  i2 = b1 ? i1 : (b2 ? ni : i2);
  v1 = b0 ? v0 : (b1 ? nv : v1);
  i1 = b0 ? i0 : (b1 ? ni : i1);
  v0 = b0 ? nv : v0;
  i0 = b0 ? ni : i0;
}

__global__ void init_k(float* __restrict__ h_seq, unsigned* __restrict__ cnt) {
  int t = blockIdx.x * 256 + threadIdx.x;   // grid 8 x 256
  if (t < 2048) h_seq[t] = 0.f;             // h_seq[0][*][*] = 0
  if (t < 1024) cnt[t] = 0u;                // barrier counters (ws is poisoned!)
}

// ---------------- generic tiled GEMM: C(MxN) = A(MxK) @ B(NxK)^T + bias ----
// AMODE 0: A plain row-major.  AMODE 1: A row r=(b*256+s) -> h_seq[(s+1)*4+b].
// AMODE 2: concat [h | A2(1024x128)], K=640.
template<int AMODE>
__global__ __launch_bounds__(256) void gemm_k(
    const float* __restrict__ A, const float* __restrict__ A2,
    const float* __restrict__ Bw, const float* __restrict__ b1,
    const float* __restrict__ b2, float* __restrict__ C,
    int M, int N, int K) {
  __shared__ float4 As4[64][16];
  __shared__ float4 Bs4[64][16];
  const int t = threadIdx.x;
  const int tx = t & 15, ty = t >> 4;
  const int brow = blockIdx.x * 64, bcol = blockIdx.y * 64;
  const int srow = t >> 2, scb = t & 3;
  float acc[4][4] = {};
  for (int kt = 0; kt < K; kt += 64) {
#pragma unroll
    for (int u = 0; u < 4; ++u) {
      int c = scb + 4 * u;           // float4 column 0..15
      int gk = kt + c * 4;
      int gr = brow + srow;
      const float* ap;
      if (AMODE == 0) {
        ap = A + (size_t)gr * K + gk;
      } else {
        int b = gr >> 8, s = gr & 255;
        const float* hrow = A + ((size_t)(s + 1) * 4 + b) * 512;
        if (AMODE == 1) ap = hrow + gk;
        else ap = (gk < 512) ? (hrow + gk) : (A2 + (size_t)gr * 128 + (gk - 512));
      }
      As4[srow][c ^ (srow & 15)] = *(const float4*)ap;
      Bs4[srow][c ^ (srow & 15)] = *(const float4*)(Bw + (size_t)(bcol + srow) * K + gk);
    }
    __syncthreads();
#pragma unroll
    for (int d4 = 0; d4 < 16; ++d4) {
      float4 av[4], bv[4];
#pragma unroll
      for (int i = 0; i < 4; ++i) av[i] = As4[ty * 4 + i][d4 ^ ((ty * 4 + i) & 15)];
#pragma unroll
      for (int j = 0; j < 4; ++j) bv[j] = Bs4[tx * 4 + j][d4 ^ ((tx * 4 + j) & 15)];
#pragma unroll
      for (int i = 0; i < 4; ++i)
#pragma unroll
        for (int j = 0; j < 4; ++j)
          acc[i][j] += av[i].x * bv[j].x + av[i].y * bv[j].y +
                       av[i].z * bv[j].z + av[i].w * bv[j].w;
    }
    __syncthreads();
  }
#pragma unroll
  for (int i = 0; i < 4; ++i) {
    int r = brow + ty * 4 + i;
#pragma unroll
    for (int j = 0; j < 4; ++j) {
      int n = bcol + tx * 4 + j;
      float bias = b1[n];
      if (b2) bias += b2[n];
      C[(size_t)r * N + n] = acc[i][j] + bias;
    }
  }
}

// ---------------- LSTM recurrence: persistent, per-step device barrier -----
__global__ __launch_bounds__(512, 1) void lstm_k(
    const float* __restrict__ xg, const float* __restrict__ W_hh,
    float* __restrict__ h_seq, unsigned* __restrict__ cnt) {
  const int bid = blockIdx.x;
  const int batch = bid >> 4;          // 16 blocks per batch
  const int ub = bid & 15;
  const int t = threadIdx.x;           // 512
  const int uu = t >> 4;               // 0..31 local unit
  const int li = t & 15;               // 16 lanes per unit, 32 d-elems each
  const int unit = ub * 32 + uu;
  __shared__ float h_lds[16 * 36];     // swizzled: idx(d) = (d>>5)*36 + (d&31)

  float w[4][32];                      // W_hh[g*512+unit][li*32 .. +32)
#pragma unroll
  for (int g = 0; g < 4; ++g) {
    const float* wr = W_hh + (size_t)(g * 512 + unit) * 512 + li * 32;
#pragma unroll
    for (int j = 0; j < 32; j += 4) {
      float4 v = *(const float4*)(wr + j);
      w[g][j] = v.x; w[g][j + 1] = v.y; w[g][j + 2] = v.z; w[g][j + 3] = v.w;
    }
  }
  float c = 0.f;
  float xgv[4];
#pragma unroll
  for (int g = 0; g < 4; ++g)
    xgv[g] = xg[(size_t)(batch * 256) * 2048 + g * 512 + unit];

  for (int step = 0; step < 256; ++step) {
    {
      float hv = h_seq[(size_t)(step * 4 + batch) * 512 + t];
      h_lds[(t >> 5) * 36 + (t & 31)] = hv;
    }
    __syncthreads();
    float a0 = 0, a1 = 0, a2 = 0, a3 = 0;
#pragma unroll
    for (int j = 0; j < 32; j += 4) {
      float4 hv = *(const float4*)(&h_lds[li * 36 + j]);
      a0 += w[0][j] * hv.x + w[0][j + 1] * hv.y + w[0][j + 2] * hv.z + w[0][j + 3] * hv.w;
      a1 += w[1][j] * hv.x + w[1][j + 1] * hv.y + w[1][j + 2] * hv.z + w[1][j + 3] * hv.w;
      a2 += w[2][j] * hv.x + w[2][j + 1] * hv.y + w[2][j + 2] * hv.z + w[2][j + 3] * hv.w;
      a3 += w[3][j] * hv.x + w[3][j + 1] * hv.y + w[3][j + 2] * hv.z + w[3][j + 3] * hv.w;
    }
#pragma unroll
    for (int m = 1; m < 16; m <<= 1) {
      a0 += __shfl_xor(a0, m, 64); a1 += __shfl_xor(a1, m, 64);
      a2 += __shfl_xor(a2, m, 64); a3 += __shfl_xor(a3, m, 64);
    }
    float gi = a0 + xgv[0], gf = a1 + xgv[1], gg = a2 + xgv[2], go = a3 + xgv[3];
    float i_ = 1.f / (1.f + expf(-gi));
    float f_ = 1.f / (1.f + expf(-gf));
    float g_ = tanhf(gg);
    float o_ = 1.f / (1.f + expf(-go));
    c = f_ * c + i_ * g_;
    float h = o_ * tanhf(c);
    if (li == 0) h_seq[(size_t)((step + 1) * 4 + batch) * 512 + unit] = h;
    if (step < 255) {
#pragma unroll
      for (int g = 0; g < 4; ++g)
        xgv[g] = xg[(size_t)(batch * 256 + step + 1) * 2048 + g * 512 + unit];
      __syncthreads();
      if (t == 0) {
        unsigned* pc = cnt + (step * 4 + batch);
        __hip_atomic_fetch_add(pc, 1u, __ATOMIC_ACQ_REL, __HIP_MEMORY_SCOPE_AGENT);
        while (__hip_atomic_load(pc, __ATOMIC_ACQUIRE, __HIP_MEMORY_SCOPE_AGENT) < 16u)
          __builtin_amdgcn_s_sleep(2);
      }
      __syncthreads();
    }
  }
}

// ---------------- q row-normalize (F.normalize, eps=1e-12) -----------------
__global__ __launch_bounds__(256) void qnorm_k(float* __restrict__ q) {
  int wv = threadIdx.x >> 6, lane = threadIdx.x & 63;
  int r = blockIdx.x * 4 + wv;
  float2 v = *(float2*)(q + (size_t)r * 128 + lane * 2);
  float ss = v.x * v.x + v.y * v.y;
#pragma unroll
  for (int m = 1; m < 64; m <<= 1) ss += __shfl_xor(ss, m, 64);
  float inv = 1.f / fmaxf(sqrtf(ss), 1e-12f);
  v.x *= inv; v.y *= inv;
  *(float2*)(q + (size_t)r * 128 + lane * 2) = v;
}

// ---------------- key inverse norms ----------------------------------------
__global__ __launch_bounds__(256) void invnorm_k(const float* __restrict__ keys,
                                                 float* __restrict__ invn) {
  int wv = threadIdx.x >> 6, lane = threadIdx.x & 63;
  int r = blockIdx.x * 4 + wv;   // grid 25000 -> exactly 100000 rows
  float2 v = *(const float2*)(keys + (size_t)r * 128 + lane * 2);
  float ss = v.x * v.x + v.y * v.y;
#pragma unroll
  for (int m = 1; m < 64; m <<= 1) ss += __shfl_xor(ss, m, 64);
  if (lane == 0) invn[r] = 1.f / fmaxf(sqrtf(ss), 1e-12f);
}

// ---------------- fused sims + per-chunk top-3 ------------------------------
// grid (16 qtiles, 32 chunks), 256 thr. q tile 64x128 in LDS (unpadded: reads
// are 16-lane broadcasts -> conflict-free). Key subtile 62x128 in LDS with
// stride-33-float4 pad; thread key rows kr = tx+16j -> bank quad 4*tx mod 32,
// conflict-free, zero per-read addr arithmetic. Keys pre-scaled by invn at
// staging. 4q x 4k micro-tile, acc in fp32 regs, limited unroll (no spill).
__global__ __launch_bounds__(256, 2) void sims_topk(
    const float* __restrict__ q, const float* __restrict__ keys,
    const float* __restrict__ invn, float* __restrict__ pvals,
    int* __restrict__ pidx) {
  const int qt = blockIdx.x;         // 16 q-tiles of 64
  const int ch = blockIdx.y;         // 32 chunks of 3125 keys
  const int kbeg = ch * 3125, klim = kbeg + 3125;
  const int t = threadIdx.x;
  const int tx = t & 15, ty = t >> 4;
  __shared__ float4 qs4[64][32];     // 32768 B
  __shared__ float4 ks4[62][33];     // 32736 B  (total 65504 <= 64 KB)
  // stage q tile (once per block)
#pragma unroll
  for (int u = 0; u < 8; ++u) {
    int p = t + 256 * u;             // 0..2047
    int row = p >> 5, c = p & 31;
    qs4[row][c] = *(const float4*)(q + (size_t)(qt * 64 + row) * 128 + c * 4);
  }
  float tv0[4], tv1[4], tv2[4]; int ti0[4], ti1[4], ti2[4];
#pragma unroll
  for (int i = 0; i < 4; ++i) {
    tv0[i] = tv1[i] = tv2[i] = -INF;
    ti0[i] = ti1[i] = ti2[i] = 0x7fffffff;
  }
  for (int k0 = kbeg; k0 < klim; k0 += 62) {
    __syncthreads();                 // prev compute done -> safe to restage
#pragma unroll
    for (int u = 0; u < 8; ++u) {
      int p = t + 256 * u;           // 62*32 = 1984 float4s
      if (p < 1984) {
        int row = p >> 5, c = p & 31;
        int gk = k0 + row;
        float4 v = make_float4(0.f, 0.f, 0.f, 0.f);
        if (gk < klim) {
          v = *(const float4*)(keys + (size_t)gk * 128 + c * 4);
          float s = invn[gk];
          v.x *= s; v.y *= s; v.z *= s; v.w *= s;
        }
        ks4[row][c] = v;
      }
    }
    __syncthreads();
    float acc[4][4] = {};
#pragma unroll 4
    for (int d4 = 0; d4 < 32; ++d4) {
      float4 bv[4];
#pragma unroll
      for (int j = 0; j < 4; ++j) {
        int kr = tx + 16 * j;
        int krs = (kr < 62) ? kr : (kr - 16);   // safe row, same bank slot
        bv[j] = ks4[krs][d4];
      }
#pragma unroll
      for (int i = 0; i < 4; ++i) {
        float4 av = qs4[ty * 4 + i][d4];        // broadcast across tx
#pragma unroll
        for (int j = 0; j < 4; ++j)
          acc[i][j] += av.x * bv[j].x + av.y * bv[j].y +
                       av.z * bv[j].z + av.w * bv[j].w;
      }
    }
    // top-3 update (keys already unit-scaled; q unit -> acc is cosine sim)
#pragma unroll
    for (int i = 0; i < 4; ++i)
#pragma unroll
      for (int j = 0; j < 4; ++j) {
        int kr = tx + 16 * j;
        int gk = k0 + kr;
        float sim = (kr < 62 && gk < klim) ? acc[i][j] : -INF;
        ins3b(tv0[i], ti0[i], tv1[i], ti1[i], tv2[i], ti2[i], sim, gk);
      }
  }
  // butterfly merge across the 16 tx lanes of each ty group (lanes contiguous)
#pragma unroll
  for (int i = 0; i < 4; ++i) {
    float v0 = tv0[i], v1 = tv1[i], v2 = tv2[i];
    int i0 = ti0[i], i1 = ti1[i], i2 = ti2[i];
#pragma unroll
    for (int m = 1; m < 16; m <<= 1) {
      float ov0 = __shfl_xor(v0, m, 64); int oi0 = __shfl_xor(i0, m, 64);
      float ov1 = __shfl_xor(v1, m, 64); int oi1 = __shfl_xor(i1, m, 64);
      float ov2 = __shfl_xor(v2, m, 64); int oi2 = __shfl_xor(i2, m, 64);
      ins3b(v0, i0, v1, i1, v2, i2, ov0, oi0);
      ins3b(v0, i0, v1, i1, v2, i2, ov1, oi1);
      ins3b(v0, i0, v1, i1, v2, i2, ov2, oi2);
    }
    if (tx == 0) {
      int qrow = qt * 64 + ty * 4 + i;
      size_t ob = ((size_t)ch * 1024 + qrow) * 3;
      pvals[ob + 0] = v0; pvals[ob + 1] = v1; pvals[ob + 2] = v2;
      pidx[ob + 0] = i0; pidx[ob + 1] = i1; pidx[ob + 2] = i2;
    }
  }
}

// ---------------- final merge + gather + attention + weighted sum ----------
__global__ __launch_bounds__(256) void attn_k(
    const float* __restrict__ pvals, const int* __restrict__ pidx,
    const float* __restrict__ mvals, const float* __restrict__ Wa,
    const float* __restrict__ ba, float* __restrict__ mem_pre) {
  int wv = threadIdx.x >> 6, lane = threadIdx.x & 63;
  int qr = blockIdx.x * 4 + wv;    // grid 256 -> 1024 queries, wave per query
  float v0 = -INF, v1 = -INF, v2 = -INF;
  int i0 = 0x7fffffff, i1 = i0, i2 = i0;
  for (int ch = 0; ch < 32; ++ch) {
    size_t base = ((size_t)ch * 1024 + qr) * 3;
#pragma unroll
    for (int e = 0; e < 3; ++e)
      ins3b(v0, i0, v1, i1, v2, i2, pvals[base + e], pidx[base + e]);
  }
  int d = lane * 2;
  float r00 = mvals[(size_t)i0 * 128 + d], r01 = mvals[(size_t)i0 * 128 + d + 1];
  float r10 = mvals[(size_t)i1 * 128 + d], r11 = mvals[(size_t)i1 * 128 + d + 1];
  float r20 = mvals[(size_t)i2 * 128 + d], r21 = mvals[(size_t)i2 * 128 + d + 1];
  float wa0 = Wa[d], wa1 = Wa[d + 1];
  float p0 = wa0 * r00 + wa1 * r01;
  float p1 = wa0 * r10 + wa1 * r11;
  float p2 = wa0 * r20 + wa1 * r21;
#pragma unroll
  for (int m = 1; m < 64; m <<= 1) {
    p0 += __shfl_xor(p0, m, 64);
    p1 += __shfl_xor(p1, m, 64);
    p2 += __shfl_xor(p2, m, 64);
  }
  float bav = ba[0];
  float l0 = p0 + bav, l1 = p1 + bav, l2 = p2 + bav;
  float mx = fmaxf(l0, fmaxf(l1, l2));
  float e0 = expf(l0 - mx), e1 = expf(l1 - mx), e2 = expf(l2 - mx);
  float s = e0 + e1 + e2;
  float a0 = e0 / s, a1 = e1 / s, a2 = e2 / s;
  mem_pre[(size_t)qr * 128 + d]     = a0 * r00 + a1 * r10 + a2 * r20;
  mem_pre[(size_t)qr * 128 + d + 1] = a0 * r01 + a1 * r11 + a2 * r21;
}

// ---------------------------------------------------------------------------
extern "C" void kernel_launch(void* const* d_in, const int* in_sizes, int n_in,
                              void* d_out, int out_size, void* d_ws, size_t ws_size,
                              hipStream_t stream) {
  (void)in_sizes; (void)n_in; (void)out_size; (void)ws_size;
  const float* x    = (const float*)d_in[0];
  const float* W_ih = (const float*)d_in[1];
  const float* W_hh = (const float*)d_in[2];
  const float* b_ih = (const float*)d_in[3];
  const float* b_hh = (const float*)d_in[4];
  const float* Wq   = (const float*)d_in[5];
  const float* bq   = (const float*)d_in[6];
  const float* Wa   = (const float*)d_in[7];
  const float* ba   = (const float*)d_in[8];
  const float* Wc   = (const float*)d_in[9];
  const float* bc   = (const float*)d_in[10];
  const float* Wo   = (const float*)d_in[11];
  const float* bo   = (const float*)d_in[12];
  const float* keys = (const float*)d_in[13];
  const float* vals = (const float*)d_in[14];

  float* ws      = (float*)d_ws;
  float* xg      = ws + 0;
  float* h_seq   = ws + 2097152;
  float* qbuf    = ws + 2623488;
  float* invn    = ws + 2754560;
  float* mem_pre = ws + 2854560;
  float* mem_cmb = ws + 2985632;
  float* pvals   = ws + 3116704;
  int*   pidx    = (int*)(ws + 3215008);
  unsigned* cnt  = (unsigned*)(ws + 3313312);

  init_k<<<8, 256, 0, stream>>>(h_seq, cnt);
  // xg = x @ W_ih^T + (b_ih + b_hh)
  gemm_k<0><<<dim3(16, 32), 256, 0, stream>>>(x, nullptr, W_ih, b_ih, b_hh, xg,
                                              1024, 2048, 256);
  invnorm_k<<<25000, 256, 0, stream>>>(keys, invn);
  lstm_k<<<64, 512, 0, stream>>>(xg, W_hh, h_seq, cnt);
  // q = h @ Wq^T + bq, then row-normalize
  gemm_k<1><<<dim3(16, 2), 256, 0, stream>>>(h_seq, nullptr, Wq, bq, nullptr,
                                             qbuf, 1024, 128, 512);
  qnorm_k<<<256, 256, 0, stream>>>(qbuf);
  sims_topk<<<dim3(16, 32), 256, 0, stream>>>(qbuf, keys, invn, pvals, pidx);
  attn_k<<<256, 256, 0, stream>>>(pvals, pidx, vals, Wa, ba, mem_pre);
  // mem = mem_pre @ Wc^T + bc
  gemm_k<0><<<dim3(16, 2), 256, 0, stream>>>(mem_pre, nullptr, Wc, bc, nullptr,
                                             mem_cmb, 1024, 128, 128);
  // out = [h | mem] @ Wo^T + bo
  gemm_k<2><<<dim3(16, 4), 256, 0, stream>>>(h_seq, mem_cmb, Wo, bo, nullptr,
                                             (float*)d_out, 1024, 256, 640);
}

// Round 3
// 1707.440 us; speedup vs baseline: 10.4925x; 1.3185x over previous
//
#include <hip/hip_runtime.h>
#include <math.h>

#define INF __builtin_inff()
#define SENT 0x7FA00000u

// ---------------- workspace layout (float offsets) ----------------
// xg      : 0        (1024 x 2048)
// h_seq   : 2097152  (257 x 4 x 512)   h_seq[t][b][u], t=0 is h0=0
// q       : 2623488  (1024 x 128)
// invn    : 2754560  (100000)
// mem_pre : 2854560  (1024 x 128)
// mem_cmb : 2985632  (1024 x 128)
// pvals   : 3116704  (32 x 1024 x 3)
// pidx    : 3215008  (32 x 1024 x 3)  int

// branchless ordered top-3 insert; ties -> lower index wins (jax top_k)
__device__ __forceinline__ void ins3b(float& v0, int& i0, float& v1, int& i1,
                                      float& v2, int& i2, float nv, int ni) {
  bool b0 = (nv > v0) || (nv == v0 && ni < i0);
  bool b1 = (nv > v1) || (nv == v1 && ni < i1);
  bool b2 = (nv > v2) || (nv == v2 && ni < i2);
  v2 = b1 ? v1 : (b2 ? nv : v2);
  i2 = b1 ? i1 : (b2 ? ni : i2);
  v1 = b0 ? v0 : (b1 ? nv : v1);
  i1 = b0 ? i0 : (b1 ? ni : i1);
  v0 = b0 ? nv : v0;
  i0 = b0 ? ni : i0;
}

// init h_seq: step 0 -> 0.0f, steps 1..256 -> sentinel (data-as-flag).
// ws is re-poisoned to 0xAA before every launch, so this must run every call.
__global__ void init_k(float* __restrict__ h_seq) {
  int t = blockIdx.x * 256 + threadIdx.x;   // grid 2056 x 256 >= 526336
  if (t < 526336) h_seq[t] = (t < 2048) ? 0.f : __uint_as_float(SENT);
}

// ---------------- generic tiled GEMM: C(MxN) = A(MxK) @ B(NxK)^T + bias ----
// AMODE 0: A plain row-major.  AMODE 1: A row r=(b*256+s) -> h_seq[(s+1)*4+b].
// AMODE 2: concat [h | A2(1024x128)], K=640.
template<int AMODE>
__global__ __launch_bounds__(256) void gemm_k(
    const float* __restrict__ A, const float* __restrict__ A2,
    const float* __restrict__ Bw, const float* __restrict__ b1,
    const float* __restrict__ b2, float* __restrict__ C,
    int M, int N, int K) {
  __shared__ float4 As4[64][16];
  __shared__ float4 Bs4[64][16];
  const int t = threadIdx.x;
  const int tx = t & 15, ty = t >> 4;
  const int brow = blockIdx.x * 64, bcol = blockIdx.y * 64;
  const int srow = t >> 2, scb = t & 3;
  float acc[4][4] = {};
  for (int kt = 0; kt < K; kt += 64) {
#pragma unroll
    for (int u = 0; u < 4; ++u) {
      int c = scb + 4 * u;           // float4 column 0..15
      int gk = kt + c * 4;
      int gr = brow + srow;
      const float* ap;
      if (AMODE == 0) {
        ap = A + (size_t)gr * K + gk;
      } else {
        int b = gr >> 8, s = gr & 255;
        const float* hrow = A + ((size_t)(s + 1) * 4 + b) * 512;
        if (AMODE == 1) ap = hrow + gk;
        else ap = (gk < 512) ? (hrow + gk) : (A2 + (size_t)gr * 128 + (gk - 512));
      }
      As4[srow][c ^ (srow & 15)] = *(const float4*)ap;
      Bs4[srow][c ^ (srow & 15)] = *(const float4*)(Bw + (size_t)(bcol + srow) * K + gk);
    }
    __syncthreads();
#pragma unroll
    for (int d4 = 0; d4 < 16; ++d4) {
      float4 av[4], bv[4];
#pragma unroll
      for (int i = 0; i < 4; ++i) av[i] = As4[ty * 4 + i][d4 ^ ((ty * 4 + i) & 15)];
#pragma unroll
      for (int j = 0; j < 4; ++j) bv[j] = Bs4[tx * 4 + j][d4 ^ ((tx * 4 + j) & 15)];
#pragma unroll
      for (int i = 0; i < 4; ++i)
#pragma unroll
        for (int j = 0; j < 4; ++j)
          acc[i][j] += av[i].x * bv[j].x + av[i].y * bv[j].y +
                       av[i].z * bv[j].z + av[i].w * bv[j].w;
    }
    __syncthreads();
  }
#pragma unroll
  for (int i = 0; i < 4; ++i) {
    int r = brow + ty * 4 + i;
#pragma unroll
    for (int j = 0; j < 4; ++j) {
      int n = bcol + tx * 4 + j;
      float bias = b1[n];
      if (b2) bias += b2[n];
      C[(size_t)r * N + n] = acc[i][j] + bias;
    }
  }
}

// ---------------- LSTM recurrence: persistent, data-as-flag sync -----------
// 64 blocks x 1024 threads. batch = bid>>4, block owns 32 units.
// Thread (gp, uu, li): gate pair gp (0:i,f  1:g,o), unit uu, 32-dim slice li.
// Per-thread W_hh slice = 2x32 floats -> stays in VGPRs (fits 128 budget).
// h exchange: producers do relaxed agent-scope atomic stores; consumers poll
// their own word until != sentinel. No counters, no fences, no grid barrier.
__global__ __launch_bounds__(1024, 4) void lstm_k(
    const float* __restrict__ xg, const float* __restrict__ W_hh,
    float* __restrict__ h_seq) {
  const int bid = blockIdx.x;
  const int batch = bid >> 4;
  const int ub = bid & 15;
  const int t = threadIdx.x;           // 1024
  const int gp = t >> 9;               // 0: gates i,f   1: gates g,o
  const int tin = t & 511;
  const int uu = tin >> 4;             // 0..31 local unit
  const int li = tin & 15;             // 16 lanes per unit, 32 dims each
  const int unit = ub * 32 + uu;
  __shared__ float h_lds[16 * 36];     // dim d at (d>>5)*36 + (d&31): 2-way max
  __shared__ float go_lds[32][2];      // (g,o) gate sums per unit

  float w[2][32];                      // W_hh[(gp*2+g2)*512+unit][li*32 ..+32)
#pragma unroll
  for (int g2 = 0; g2 < 2; ++g2) {
    const float* wr = W_hh + (size_t)((gp * 2 + g2) * 512 + unit) * 512 + li * 32;
#pragma unroll
    for (int j = 0; j < 32; j += 4) {
      float4 v = *(const float4*)(wr + j);
      w[g2][j] = v.x; w[g2][j + 1] = v.y; w[g2][j + 2] = v.z; w[g2][j + 3] = v.w;
    }
  }
  float c = 0.f;
  float xgv[2];
#pragma unroll
  for (int g2 = 0; g2 < 2; ++g2)
    xgv[g2] = xg[(size_t)(batch * 256) * 2048 + (gp * 2 + g2) * 512 + unit];

  for (int step = 0; step < 256; ++step) {
    if (t < 512) {                     // poll own word, stage into LDS
      const float* hp = h_seq + ((size_t)step * 4 + batch) * 512 + t;
      float hv;
      do {
        hv = __hip_atomic_load(hp, __ATOMIC_RELAXED, __HIP_MEMORY_SCOPE_AGENT);
      } while (__float_as_uint(hv) == SENT);
      h_lds[((t >> 5) * 36) + (t & 31)] = hv;
    }
    __syncthreads();
    float a0 = 0.f, a1 = 0.f;
#pragma unroll
    for (int j = 0; j < 32; j += 4) {
      float4 hv = *(const float4*)(&h_lds[li * 36 + j]);
      a0 += w[0][j] * hv.x + w[0][j + 1] * hv.y + w[0][j + 2] * hv.z + w[0][j + 3] * hv.w;
      a1 += w[1][j] * hv.x + w[1][j + 1] * hv.y + w[1][j + 2] * hv.z + w[1][j + 3] * hv.w;
    }
#pragma unroll
    for (int m = 1; m < 16; m <<= 1) { // reduce 16 lanes of the unit
      a0 += __shfl_xor(a0, m, 64);
      a1 += __shfl_xor(a1, m, 64);
    }
    a0 += xgv[0]; a1 += xgv[1];        // add input-gate preactivations
    if (gp == 1 && li == 0) { go_lds[uu][0] = a0; go_lds[uu][1] = a1; }
    __syncthreads();
    if (step < 255) {                  // prefetch next xg (L2 hit)
#pragma unroll
      for (int g2 = 0; g2 < 2; ++g2)
        xgv[g2] = xg[(size_t)(batch * 256 + step + 1) * 2048 + (gp * 2 + g2) * 512 + unit];
    }
    if (gp == 0) {                     // all 16 lanes redundantly carry c
      float i_ = 1.f / (1.f + expf(-a0));
      float f_ = 1.f / (1.f + expf(-a1));
      float g_ = tanhf(go_lds[uu][0]);
      float o_ = 1.f / (1.f + expf(-go_lds[uu][1]));
      c = f_ * c + i_ * g_;
      float h = o_ * tanhf(c);
      if (li == 0)
        __hip_atomic_store(h_seq + ((size_t)(step + 1) * 4 + batch) * 512 + unit,
                           h, __ATOMIC_RELAXED, __HIP_MEMORY_SCOPE_AGENT);
    }
  }
}

// ---------------- q row-normalize (F.normalize, eps=1e-12) -----------------
__global__ __launch_bounds__(256) void qnorm_k(float* __restrict__ q) {
  int wv = threadIdx.x >> 6, lane = threadIdx.x & 63;
  int r = blockIdx.x * 4 + wv;
  float2 v = *(float2*)(q + (size_t)r * 128 + lane * 2);
  float ss = v.x * v.x + v.y * v.y;
#pragma unroll
  for (int m = 1; m < 64; m <<= 1) ss += __shfl_xor(ss, m, 64);
  float inv = 1.f / fmaxf(sqrtf(ss), 1e-12f);
  v.x *= inv; v.y *= inv;
  *(float2*)(q + (size_t)r * 128 + lane * 2) = v;
}

// ---------------- key inverse norms ----------------------------------------
__global__ __launch_bounds__(256) void invnorm_k(const float* __restrict__ keys,
                                                 float* __restrict__ invn) {
  int wv = threadIdx.x >> 6, lane = threadIdx.x & 63;
  int r = blockIdx.x * 4 + wv;   // grid 25000 -> exactly 100000 rows
  float2 v = *(const float2*)(keys + (size_t)r * 128 + lane * 2);
  float ss = v.x * v.x + v.y * v.y;
#pragma unroll
  for (int m = 1; m < 64; m <<= 1) ss += __shfl_xor(ss, m, 64);
  if (lane == 0) invn[r] = 1.f / fmaxf(sqrtf(ss), 1e-12f);
}

// ---------------- fused sims + per-chunk top-3 ------------------------------
// grid (16 qtiles, 32 chunks), 256 thr. q tile 64x128 in LDS (unpadded: reads
// are 16-lane broadcasts -> conflict-free). Key subtile 62x128 in LDS with
// stride-33-float4 pad; thread key rows kr = tx+16j -> bank quad 4*tx mod 32,
// conflict-free, zero per-read addr arithmetic. Keys pre-scaled by invn at
// staging. 4q x 4k micro-tile, acc in fp32 regs, limited unroll (no spill).
__global__ __launch_bounds__(256, 2) void sims_topk(
    const float* __restrict__ q, const float* __restrict__ keys,
    const float* __restrict__ invn, float* __restrict__ pvals,
    int* __restrict__ pidx) {
  const int qt = blockIdx.x;         // 16 q-tiles of 64
  const int ch = blockIdx.y;         // 32 chunks of 3125 keys
  const int kbeg = ch * 3125, klim = kbeg + 3125;
  const int t = threadIdx.x;
  const int tx = t & 15, ty = t >> 4;
  __shared__ float4 qs4[64][32];     // 32768 B
  __shared__ float4 ks4[62][33];     // 32736 B  (total 65504 <= 64 KB)
  // stage q tile (once per block)
#pragma unroll
  for (int u = 0; u < 8; ++u) {
    int p = t + 256 * u;             // 0..2047
    int row = p >> 5, c = p & 31;
    qs4[row][c] = *(const float4*)(q + (size_t)(qt * 64 + row) * 128 + c * 4);
  }
  float tv0[4], tv1[4], tv2[4]; int ti0[4], ti1[4], ti2[4];
#pragma unroll
  for (int i = 0; i < 4; ++i) {
    tv0[i] = tv1[i] = tv2[i] = -INF;
    ti0[i] = ti1[i] = ti2[i] = 0x7fffffff;
  }
  for (int k0 = kbeg; k0 < klim; k0 += 62) {
    __syncthreads();                 // prev compute done -> safe to restage
#pragma unroll
    for (int u = 0; u < 8; ++u) {
      int p = t + 256 * u;           // 62*32 = 1984 float4s
      if (p < 1984) {
        int row = p >> 5, c = p & 31;
        int gk = k0 + row;
        float4 v = make_float4(0.f, 0.f, 0.f, 0.f);
        if (gk < klim) {
          v = *(const float4*)(keys + (size_t)gk * 128 + c * 4);
          float s = invn[gk];
          v.x *= s; v.y *= s; v.z *= s; v.w *= s;
        }
        ks4[row][c] = v;
      }
    }
    __syncthreads();
    float acc[4][4] = {};
#pragma unroll 4
    for (int d4 = 0; d4 < 32; ++d4) {
      float4 bv[4];
#pragma unroll
      for (int j = 0; j < 4; ++j) {
        int kr = tx + 16 * j;
        int krs = (kr < 62) ? kr : (kr - 16);   // safe row, same bank slot
        bv[j] = ks4[krs][d4];
      }
#pragma unroll
      for (int i = 0; i < 4; ++i) {
        float4 av = qs4[ty * 4 + i][d4];        // broadcast across tx
#pragma unroll
        for (int j = 0; j < 4; ++j)
          acc[i][j] += av.x * bv[j].x + av.y * bv[j].y +
                       av.z * bv[j].z + av.w * bv[j].w;
      }
    }
    // top-3 update (keys already unit-scaled; q unit -> acc is cosine sim)
#pragma unroll
    for (int i = 0; i < 4; ++i)
#pragma unroll
      for (int j = 0; j < 4; ++j) {
        int kr = tx + 16 * j;
        int gk = k0 + kr;
        float sim = (kr < 62 && gk < klim) ? acc[i][j] : -INF;
        ins3b(tv0[i], ti0[i], tv1[i], ti1[i], tv2[i], ti2[i], sim, gk);
      }
  }
  // butterfly merge across the 16 tx lanes of each ty group (lanes contiguous)
#pragma unroll
  for (int i = 0; i < 4; ++i) {
    float v0 = tv0[i], v1 = tv1[i], v2 = tv2[i];
    int i0 = ti0[i], i1 = ti1[i], i2 = ti2[i];
#pragma unroll
    for (int m = 1; m < 16; m <<= 1) {
      float ov0 = __shfl_xor(v0, m, 64); int oi0 = __shfl_xor(i0, m, 64);
      float ov1 = __shfl_xor(v1, m, 64); int oi1 = __shfl_xor(i1, m, 64);
      float ov2 = __shfl_xor(v2, m, 64); int oi2 = __shfl_xor(i2, m, 64);
      ins3b(v0, i0, v1, i1, v2, i2, ov0, oi0);
      ins3b(v0, i0, v1, i1, v2, i2, ov1, oi1);
      ins3b(v0, i0, v1, i1, v2, i2, ov2, oi2);
    }
    if (tx == 0) {
      int qrow = qt * 64 + ty * 4 + i;
      size_t ob = ((size_t)ch * 1024 + qrow) * 3;
      pvals[ob + 0] = v0; pvals[ob + 1] = v1; pvals[ob + 2] = v2;
      pidx[ob + 0] = i0; pidx[ob + 1] = i1; pidx[ob + 2] = i2;
    }
  }
}

// ---------------- final merge + gather + attention + weighted sum ----------
__global__ __launch_bounds__(256) void attn_k(
    const float* __restrict__ pvals, const int* __restrict__ pidx,
    const float* __restrict__ mvals, const float* __restrict__ Wa,
    const float* __restrict__ ba, float* __restrict__ mem_pre) {
  int wv = threadIdx.x >> 6, lane = threadIdx.x & 63;
  int qr = blockIdx.x * 4 + wv;    // grid 256 -> 1024 queries, wave per query
  float v0 = -INF, v1 = -INF, v2 = -INF;
  int i0 = 0x7fffffff, i1 = i0, i2 = i0;
  for (int ch = 0; ch < 32; ++ch) {
    size_t base = ((size_t)ch * 1024 + qr) * 3;
#pragma unroll
    for (int e = 0; e < 3; ++e)
      ins3b(v0, i0, v1, i1, v2, i2, pvals[base + e], pidx[base + e]);
  }
  int d = lane * 2;
  float r00 = mvals[(size_t)i0 * 128 + d], r01 = mvals[(size_t)i0 * 128 + d + 1];
  float r10 = mvals[(size_t)i1 * 128 + d], r11 = mvals[(size_t)i1 * 128 + d + 1];
  float r20 = mvals[(size_t)i2 * 128 + d], r21 = mvals[(size_t)i2 * 128 + d + 1];
  float wa0 = Wa[d], wa1 = Wa[d + 1];
  float p0 = wa0 * r00 + wa1 * r01;
  float p1 = wa0 * r10 + wa1 * r11;
  float p2 = wa0 * r20 + wa1 * r21;
#pragma unroll
  for (int m = 1; m < 64; m <<= 1) {
    p0 += __shfl_xor(p0, m, 64);
    p1 += __shfl_xor(p1, m, 64);
    p2 += __shfl_xor(p2, m, 64);
  }
  float bav = ba[0];
  float l0 = p0 + bav, l1 = p1 + bav, l2 = p2 + bav;
  float mx = fmaxf(l0, fmaxf(l1, l2));
  float e0 = expf(l0 - mx), e1 = expf(l1 - mx), e2 = expf(l2 - mx);
  float s = e0 + e1 + e2;
  float a0 = e0 / s, a1 = e1 / s, a2 = e2 / s;
  mem_pre[(size_t)qr * 128 + d]     = a0 * r00 + a1 * r10 + a2 * r20;
  mem_pre[(size_t)qr * 128 + d + 1] = a0 * r01 + a1 * r11 + a2 * r21;
}

// ---------------------------------------------------------------------------
extern "C" void kernel_launch(void* const* d_in, const int* in_sizes, int n_in,
                              void* d_out, int out_size, void* d_ws, size_t ws_size,
                              hipStream_t stream) {
  (void)in_sizes; (void)n_in; (void)out_size; (void)ws_size;
  const float* x    = (const float*)d_in[0];
  const float* W_ih = (const float*)d_in[1];
  const float* W_hh = (const float*)d_in[2];
  const float* b_ih = (const float*)d_in[3];
  const float* b_hh = (const float*)d_in[4];
  const float* Wq   = (const float*)d_in[5];
  const float* bq   = (const float*)d_in[6];
  const float* Wa   = (const float*)d_in[7];
  const float* ba   = (const float*)d_in[8];
  const float* Wc   = (const float*)d_in[9];
  const float* bc   = (const float*)d_in[10];
  const float* Wo   = (const float*)d_in[11];
  const float* bo   = (const float*)d_in[12];
  const float* keys = (const float*)d_in[13];
  const float* vals = (const float*)d_in[14];

  float* ws      = (float*)d_ws;
  float* xg      = ws + 0;
  float* h_seq   = ws + 2097152;
  float* qbuf    = ws + 2623488;
  float* invn    = ws + 2754560;
  float* mem_pre = ws + 2854560;
  float* mem_cmb = ws + 2985632;
  float* pvals   = ws + 3116704;
  int*   pidx    = (int*)(ws + 3215008);

  init_k<<<2056, 256, 0, stream>>>(h_seq);
  // xg = x @ W_ih^T + (b_ih + b_hh)
  gemm_k<0><<<dim3(16, 32), 256, 0, stream>>>(x, nullptr, W_ih, b_ih, b_hh, xg,
                                              1024, 2048, 256);
  invnorm_k<<<25000, 256, 0, stream>>>(keys, invn);
  lstm_k<<<64, 1024, 0, stream>>>(xg, W_hh, h_seq);
  // q = h @ Wq^T + bq, then row-normalize
  gemm_k<1><<<dim3(16, 2), 256, 0, stream>>>(h_seq, nullptr, Wq, bq, nullptr,
                                             qbuf, 1024, 128, 512);
  qnorm_k<<<256, 256, 0, stream>>>(qbuf);
  sims_topk<<<dim3(16, 32), 256, 0, stream>>>(qbuf, keys, invn, pvals, pidx);
  attn_k<<<256, 256, 0, stream>>>(pvals, pidx, vals, Wa, ba, mem_pre);
  // mem = mem_pre @ Wc^T + bc
  gemm_k<0><<<dim3(16, 2), 256, 0, stream>>>(mem_pre, nullptr, Wc, bc, nullptr,
                                             mem_cmb, 1024, 128, 128);
  // out = [h | mem] @ Wo^T + bo
  gemm_k<2><<<dim3(16, 4), 256, 0, stream>>>(h_seq, mem_cmb, Wo, bo, nullptr,
                                             (float*)d_out, 1024, 256, 640);
}

// Round 4
// 1209.805 us; speedup vs baseline: 14.8084x; 1.4113x over previous
//
#include <hip/hip_runtime.h>
#include <math.h>

#define INF __builtin_inff()
#define SENT 0x7FA00000u
#define IMAX 0x7fffffff

typedef __attribute__((ext_vector_type(8))) short bhalf8;
typedef __attribute__((ext_vector_type(4))) float f32x4;

// ---------------- workspace layout (float offsets) ----------------
// xg      : 0        (1024 x 2048)
// h_seq   : 2097152  (257 x 4 x 512)
// qbuf    : 2623488  (1024 x 128)  fp32 normalized q
// invn    : 2754560  (100000)
// mem_pre : 2854560  (1024 x 128)
// mem_cmb : 2985632  (1024 x 128)
// pvals   : 3116704  (32 x 1024 x 6)
// pidx    : 3313312  (32 x 1024 x 6) int
// qbf     : 3509920  (1024 x 64 uint)   bf16x2 normalized q
// kbf     : 3575456  (100000 x 64 uint) bf16x2 unit-scaled keys -> end 9975456

// branchless ordered top-3 insert; ties -> lower index wins (jax top_k)
__device__ __forceinline__ void ins3b(float& v0, int& i0, float& v1, int& i1,
                                      float& v2, int& i2, float nv, int ni) {
  bool b0 = (nv > v0) || (nv == v0 && ni < i0);
  bool b1 = (nv > v1) || (nv == v1 && ni < i1);
  bool b2 = (nv > v2) || (nv == v2 && ni < i2);
  v2 = b1 ? v1 : (b2 ? nv : v2);
  i2 = b1 ? i1 : (b2 ? ni : i2);
  v1 = b0 ? v0 : (b1 ? nv : v1);
  i1 = b0 ? i0 : (b1 ? ni : i1);
  v0 = b0 ? nv : v0;
  i0 = b0 ? ni : i0;
}

__device__ __forceinline__ unsigned short f2bf(float x) {  // RNE
  unsigned u = __float_as_uint(x);
  return (unsigned short)((u + 0x7FFFu + ((u >> 16) & 1u)) >> 16);
}

__global__ void init_k(float* __restrict__ h_seq) {
  int t = blockIdx.x * 256 + threadIdx.x;   // grid 2056 x 256
  if (t < 526336) h_seq[t] = (t < 2048) ? 0.f : __uint_as_float(SENT);
}

// ---------------- generic tiled GEMM: C(MxN) = A(MxK) @ B(NxK)^T + bias ----
template<int AMODE>
__global__ __launch_bounds__(256) void gemm_k(
    const float* __restrict__ A, const float* __restrict__ A2,
    const float* __restrict__ Bw, const float* __restrict__ b1,
    const float* __restrict__ b2, float* __restrict__ C,
    int M, int N, int K) {
  __shared__ float4 As4[64][16];
  __shared__ float4 Bs4[64][16];
  const int t = threadIdx.x;
  const int tx = t & 15, ty = t >> 4;
  const int brow = blockIdx.x * 64, bcol = blockIdx.y * 64;
  const int srow = t >> 2, scb = t & 3;
  float acc[4][4] = {};
  for (int kt = 0; kt < K; kt += 64) {
#pragma unroll
    for (int u = 0; u < 4; ++u) {
      int c = scb + 4 * u;
      int gk = kt + c * 4;
      int gr = brow + srow;
      const float* ap;
      if (AMODE == 0) {
        ap = A + (size_t)gr * K + gk;
      } else {
        int b = gr >> 8, s = gr & 255;
        const float* hrow = A + ((size_t)(s + 1) * 4 + b) * 512;
        if (AMODE == 1) ap = hrow + gk;
        else ap = (gk < 512) ? (hrow + gk) : (A2 + (size_t)gr * 128 + (gk - 512));
      }
      As4[srow][c ^ (srow & 15)] = *(const float4*)ap;
      Bs4[srow][c ^ (srow & 15)] = *(const float4*)(Bw + (size_t)(bcol + srow) * K + gk);
    }
    __syncthreads();
#pragma unroll
    for (int d4 = 0; d4 < 16; ++d4) {
      float4 av[4], bv[4];
#pragma unroll
      for (int i = 0; i < 4; ++i) av[i] = As4[ty * 4 + i][d4 ^ ((ty * 4 + i) & 15)];
#pragma unroll
      for (int j = 0; j < 4; ++j) bv[j] = Bs4[tx * 4 + j][d4 ^ ((tx * 4 + j) & 15)];
#pragma unroll
      for (int i = 0; i < 4; ++i)
#pragma unroll
        for (int j = 0; j < 4; ++j)
          acc[i][j] += av[i].x * bv[j].x + av[i].y * bv[j].y +
                       av[i].z * bv[j].z + av[i].w * bv[j].w;
    }
    __syncthreads();
  }
#pragma unroll
  for (int i = 0; i < 4; ++i) {
    int r = brow + ty * 4 + i;
#pragma unroll
    for (int j = 0; j < 4; ++j) {
      int n = bcol + tx * 4 + j;
      float bias = b1[n];
      if (b2) bias += b2[n];
      C[(size_t)r * N + n] = acc[i][j] + bias;
    }
  }
}

// ---------------- LSTM recurrence: persistent, data-as-flag sync -----------
__global__ __launch_bounds__(1024, 4) void lstm_k(
    const float* __restrict__ xg, const float* __restrict__ W_hh,
    float* __restrict__ h_seq) {
  const int bid = blockIdx.x;
  const int batch = bid >> 4;
  const int ub = bid & 15;
  const int t = threadIdx.x;
  const int gp = t >> 9;
  const int tin = t & 511;
  const int uu = tin >> 4;
  const int li = tin & 15;
  const int unit = ub * 32 + uu;
  __shared__ float h_lds[16 * 36];
  __shared__ float go_lds[32][2];

  float w[2][32];
#pragma unroll
  for (int g2 = 0; g2 < 2; ++g2) {
    const float* wr = W_hh + (size_t)((gp * 2 + g2) * 512 + unit) * 512 + li * 32;
#pragma unroll
    for (int j = 0; j < 32; j += 4) {
      float4 v = *(const float4*)(wr + j);
      w[g2][j] = v.x; w[g2][j + 1] = v.y; w[g2][j + 2] = v.z; w[g2][j + 3] = v.w;
    }
  }
  float c = 0.f;
  float xgv[2];
#pragma unroll
  for (int g2 = 0; g2 < 2; ++g2)
    xgv[g2] = xg[(size_t)(batch * 256) * 2048 + (gp * 2 + g2) * 512 + unit];

  for (int step = 0; step < 256; ++step) {
    if (t < 512) {
      const float* hp = h_seq + ((size_t)step * 4 + batch) * 512 + t;
      float hv;
      do {
        hv = __hip_atomic_load(hp, __ATOMIC_RELAXED, __HIP_MEMORY_SCOPE_AGENT);
      } while (__float_as_uint(hv) == SENT);
      h_lds[((t >> 5) * 36) + (t & 31)] = hv;
    }
    __syncthreads();
    float a0 = 0.f, a1 = 0.f;
#pragma unroll
    for (int j = 0; j < 32; j += 4) {
      float4 hv = *(const float4*)(&h_lds[li * 36 + j]);
      a0 += w[0][j] * hv.x + w[0][j + 1] * hv.y + w[0][j + 2] * hv.z + w[0][j + 3] * hv.w;
      a1 += w[1][j] * hv.x + w[1][j + 1] * hv.y + w[1][j + 2] * hv.z + w[1][j + 3] * hv.w;
    }
#pragma unroll
    for (int m = 1; m < 16; m <<= 1) {
      a0 += __shfl_xor(a0, m, 64);
      a1 += __shfl_xor(a1, m, 64);
    }
    a0 += xgv[0]; a1 += xgv[1];
    if (gp == 1 && li == 0) { go_lds[uu][0] = a0; go_lds[uu][1] = a1; }
    __syncthreads();
    if (step < 255) {
#pragma unroll
      for (int g2 = 0; g2 < 2; ++g2)
        xgv[g2] = xg[(size_t)(batch * 256 + step + 1) * 2048 + (gp * 2 + g2) * 512 + unit];
    }
    if (gp == 0) {
      float i_ = 1.f / (1.f + expf(-a0));
      float f_ = 1.f / (1.f + expf(-a1));
      float g_ = tanhf(go_lds[uu][0]);
      float o_ = 1.f / (1.f + expf(-go_lds[uu][1]));
      c = f_ * c + i_ * g_;
      float h = o_ * tanhf(c);
      if (li == 0)
        __hip_atomic_store(h_seq + ((size_t)(step + 1) * 4 + batch) * 512 + unit,
                           h, __ATOMIC_RELAXED, __HIP_MEMORY_SCOPE_AGENT);
    }
  }
}

// ---------------- q row-normalize + bf16 pack ------------------------------
__global__ __launch_bounds__(256) void qnorm_k(float* __restrict__ q,
                                               unsigned* __restrict__ qbf) {
  int wv = threadIdx.x >> 6, lane = threadIdx.x & 63;
  int r = blockIdx.x * 4 + wv;
  float2 v = *(float2*)(q + (size_t)r * 128 + lane * 2);
  float ss = v.x * v.x + v.y * v.y;
#pragma unroll
  for (int m = 1; m < 64; m <<= 1) ss += __shfl_xor(ss, m, 64);
  float inv = 1.f / fmaxf(sqrtf(ss), 1e-12f);
  v.x *= inv; v.y *= inv;
  *(float2*)(q + (size_t)r * 128 + lane * 2) = v;
  qbf[(size_t)r * 64 + lane] = (unsigned)f2bf(v.x) | ((unsigned)f2bf(v.y) << 16);
}

// ---------------- key inverse norms + unit-scaled bf16 keys ----------------
__global__ __launch_bounds__(256) void convk_k(const float* __restrict__ keys,
                                               float* __restrict__ invn,
                                               unsigned* __restrict__ kbf) {
  int wv = threadIdx.x >> 6, lane = threadIdx.x & 63;
  int r = blockIdx.x * 4 + wv;   // grid 25000 -> 100000 rows
  float2 v = *(const float2*)(keys + (size_t)r * 128 + lane * 2);
  float ss = v.x * v.x + v.y * v.y;
#pragma unroll
  for (int m = 1; m < 64; m <<= 1) ss += __shfl_xor(ss, m, 64);
  float inv = 1.f / fmaxf(sqrtf(ss), 1e-12f);
  if (lane == 0) invn[r] = inv;
  kbf[(size_t)r * 64 + lane] =
      (unsigned)f2bf(v.x * inv) | ((unsigned)f2bf(v.y * inv) << 16);
}

// stage one 64x128-bf16 tile: LINEAR LDS dest (global_load_lds), source
// pre-swizzled so readers can XOR-deswizzle: slot c holds dims (c^(row&7))*8..
__device__ __forceinline__ void stage_tile(unsigned short* dst,
                                           const unsigned* src,
                                           int baserow, int maxrow,
                                           int w, int l) {
#pragma unroll
  for (int u = 0; u < 4; ++u) {
    int s = u * 256 + w * 64 + l;
    int row = s >> 4, cc = s & 15;
    int gr = baserow + row; gr = gr > maxrow ? maxrow : gr;
    const unsigned* sp = src + (size_t)gr * 64 + ((cc ^ (row & 7)) << 2);
    __builtin_amdgcn_global_load_lds(
        (const __attribute__((address_space(1))) unsigned*)sp,
        (__attribute__((address_space(3))) unsigned*)(dst + (size_t)(u * 256 + w * 64) * 8),
        16, 0, 0);
  }
}

// ---------------- bf16 MFMA sims + per-chunk top-6 candidates --------------
// grid (16 q-tiles, 32 chunks of 3125), 256 thr = 4 waves. Per step: 64 keys,
// 16 mfma_f32_16x16x32_bf16 per wave; per-thread running top-3; end: 16-lane
// merge -> chunk top-6 per q-row. Double-buffered LDS, one barrier per step.
__global__ __launch_bounds__(256, 2) void simsmfma_k(
    const unsigned* __restrict__ qbf, const unsigned* __restrict__ kbf,
    float* __restrict__ pvals, int* __restrict__ pidx) {
  const int qt = blockIdx.x, ch = blockIdx.y;
  const int kbeg = ch * 3125, klim = kbeg + 3125;   // 49 steps of 64
  const int t = threadIdx.x, l = t & 63, w = t >> 6;
  __shared__ alignas(16) unsigned short ks0[8192];
  __shared__ alignas(16) unsigned short ks1[8192];

  // prologue: q tile -> ks1, read a-frags, key step0 -> ks0
  stage_tile(ks1, qbf, qt * 64, 1023, w, l);
  __syncthreads();
  bhalf8 afrag[4];
  {
    int row = w * 16 + (l & 15);
#pragma unroll
    for (int db = 0; db < 4; ++db) {
      int cslot = db * 4 + (l >> 4);
      afrag[db] = *(const bhalf8*)&ks1[(size_t)(row * 16 + (cslot ^ (row & 7))) * 8];
    }
  }
  stage_tile(ks0, kbf, kbeg, klim - 1, w, l);
  __syncthreads();

  float tv0[4], tv1[4], tv2[4]; int ti0[4], ti1[4], ti2[4];
#pragma unroll
  for (int r = 0; r < 4; ++r) {
    tv0[r] = tv1[r] = tv2[r] = -INF;
    ti0[r] = ti1[r] = ti2[r] = IMAX;
  }

  for (int s = 0; s < 49; ++s) {
    unsigned short* cur = (s & 1) ? ks1 : ks0;
    unsigned short* nxt = (s & 1) ? ks0 : ks1;
    if (s < 48) stage_tile(nxt, kbf, kbeg + (s + 1) * 64, klim - 1, w, l);
    int k0 = kbeg + s * 64;

    f32x4 ac0 = {0,0,0,0}, ac1 = {0,0,0,0}, ac2 = {0,0,0,0}, ac3 = {0,0,0,0};
    const int r0 = l & 15;
#pragma unroll
    for (int db = 0; db < 4; ++db) {
      int swz = (db * 4 + (l >> 4)) ^ (r0 & 7);
      bhalf8 b0 = *(const bhalf8*)&cur[(size_t)((r0     ) * 16 + swz) * 8];
      bhalf8 b1 = *(const bhalf8*)&cur[(size_t)((r0 + 16) * 16 + swz) * 8];
      bhalf8 b2 = *(const bhalf8*)&cur[(size_t)((r0 + 32) * 16 + swz) * 8];
      bhalf8 b3 = *(const bhalf8*)&cur[(size_t)((r0 + 48) * 16 + swz) * 8];
      ac0 = __builtin_amdgcn_mfma_f32_16x16x32_bf16(afrag[db], b0, ac0, 0, 0, 0);
      ac1 = __builtin_amdgcn_mfma_f32_16x16x32_bf16(afrag[db], b1, ac1, 0, 0, 0);
      ac2 = __builtin_amdgcn_mfma_f32_16x16x32_bf16(afrag[db], b2, ac2, 0, 0, 0);
      ac3 = __builtin_amdgcn_mfma_f32_16x16x32_bf16(afrag[db], b3, ac3, 0, 0, 0);
    }
    // lane's D entries: q-row-local = w*16+(l>>4)*4+r, key = k0+nt*16+(l&15)
#pragma unroll
    for (int nt = 0; nt < 4; ++nt) {
      f32x4 a = (nt == 0) ? ac0 : (nt == 1) ? ac1 : (nt == 2) ? ac2 : ac3;
      int gk = k0 + nt * 16 + (l & 15);
      bool ok = gk < klim;
#pragma unroll
      for (int r = 0; r < 4; ++r) {
        float v = ok ? a[r] : -INF;
        ins3b(tv0[r], ti0[r], tv1[r], ti1[r], tv2[r], ti2[r], v, gk);
      }
    }
    __syncthreads();
  }

  // 16-lane merge (fixed l>>4 group) -> chunk top-6 per q-row
#pragma unroll
  for (int r = 0; r < 4; ++r) {
    float c0 = tv0[r], c1 = tv1[r], c2 = tv2[r];
    int j0 = ti0[r], j1 = ti1[r], j2 = ti2[r];
    int qrow = qt * 64 + w * 16 + (l >> 4) * 4 + r;
    size_t ob = ((size_t)ch * 1024 + qrow) * 6;
#pragma unroll
    for (int e = 0; e < 6; ++e) {
      float mv = c0; int mi = j0;
#pragma unroll
      for (int m = 1; m < 16; m <<= 1) {
        float o = __shfl_xor(mv, m, 64); int oi = __shfl_xor(mi, m, 64);
        bool tk = (o > mv) || (o == mv && oi < mi);
        mv = tk ? o : mv; mi = tk ? oi : mi;
      }
      if (mi == j0) { c0 = c1; j0 = j1; c1 = c2; j1 = j2; c2 = -INF; j2 = IMAX; }
      if ((l & 15) == 0) { pvals[ob + e] = mv; pidx[ob + e] = mi; }
    }
  }
}

// ---------------- merge chunks + fp32 rescore + attention ------------------
// wave per query: merge 32x6 approx candidates -> top-8, rescore exactly in
// fp32 (q.k * invn), exact top-3 (jax tie order), gather values, softmax, sum.
__global__ __launch_bounds__(256) void merge_rescore_k(
    const float* __restrict__ pvals, const int* __restrict__ pidx,
    const float* __restrict__ qf, const float* __restrict__ keys,
    const float* __restrict__ invn, const float* __restrict__ mvals,
    const float* __restrict__ Wa, const float* __restrict__ ba,
    float* __restrict__ mem_pre) {
  int wv = threadIdx.x >> 6, l = threadIdx.x & 63;
  int qr = blockIdx.x * 4 + wv;   // grid 256 -> 1024 queries
  // lane holds 3 of the 192 candidates, sorted
  float h0 = -INF, h1 = -INF, h2 = -INF;
  int g0 = IMAX, g1 = IMAX, g2 = IMAX;
#pragma unroll
  for (int e = 0; e < 3; ++e) {
    int c = l * 3 + e;
    size_t base = ((size_t)(c / 6) * 1024 + qr) * 6 + (c % 6);
    ins3b(h0, g0, h1, g1, h2, g2, pvals[base], pidx[base]);
  }
  // extract approx top-8 across 64 lanes
  float sc[8]; int si[8];
#pragma unroll
  for (int e = 0; e < 8; ++e) {
    float mv = h0; int mi = g0;
#pragma unroll
    for (int m = 1; m < 64; m <<= 1) {
      float o = __shfl_xor(mv, m, 64); int oi = __shfl_xor(mi, m, 64);
      bool tk = (o > mv) || (o == mv && oi < mi);
      mv = tk ? o : mv; mi = tk ? oi : mi;
    }
    sc[e] = mv; si[e] = mi;
    if (mi == g0) { h0 = h1; g0 = g1; h1 = h2; g1 = g2; h2 = -INF; g2 = IMAX; }
  }
  // exact fp32 rescore of the 8
  int d = l * 2;
  float q0 = qf[(size_t)qr * 128 + d], q1 = qf[(size_t)qr * 128 + d + 1];
  float ex[8];
#pragma unroll
  for (int e = 0; e < 8; ++e) {
    int k = si[e];
    float p = q0 * keys[(size_t)k * 128 + d] + q1 * keys[(size_t)k * 128 + d + 1];
#pragma unroll
    for (int m = 1; m < 64; m <<= 1) p += __shfl_xor(p, m, 64);
    ex[e] = p * invn[k];
  }
  // exact top-3 (replicated in all lanes)
  float v0 = -INF, v1 = -INF, v2 = -INF;
  int i0 = IMAX, i1 = IMAX, i2 = IMAX;
#pragma unroll
  for (int e = 0; e < 8; ++e) ins3b(v0, i0, v1, i1, v2, i2, ex[e], si[e]);
  // gather value rows + attention
  float r00 = mvals[(size_t)i0 * 128 + d], r01 = mvals[(size_t)i0 * 128 + d + 1];
  float r10 = mvals[(size_t)i1 * 128 + d], r11 = mvals[(size_t)i1 * 128 + d + 1];
  float r20 = mvals[(size_t)i2 * 128 + d], r21 = mvals[(size_t)i2 * 128 + d + 1];
  float wa0 = Wa[d], wa1 = Wa[d + 1];
  float p0 = wa0 * r00 + wa1 * r01;
  float p1 = wa0 * r10 + wa1 * r11;
  float p2 = wa0 * r20 + wa1 * r21;
#pragma unroll
  for (int m = 1; m < 64; m <<= 1) {
    p0 += __shfl_xor(p0, m, 64);
    p1 += __shfl_xor(p1, m, 64);
    p2 += __shfl_xor(p2, m, 64);
  }
  float bav = ba[0];
  float l0 = p0 + bav, l1 = p1 + bav, l2 = p2 + bav;
  float mx = fmaxf(l0, fmaxf(l1, l2));
  float e0 = expf(l0 - mx), e1 = expf(l1 - mx), e2 = expf(l2 - mx);
  float s = e0 + e1 + e2;
  float a0 = e0 / s, a1 = e1 / s, a2 = e2 / s;
  mem_pre[(size_t)qr * 128 + d]     = a0 * r00 + a1 * r10 + a2 * r20;
  mem_pre[(size_t)qr * 128 + d + 1] = a0 * r01 + a1 * r11 + a2 * r21;
}

// ---------------------------------------------------------------------------
extern "C" void kernel_launch(void* const* d_in, const int* in_sizes, int n_in,
                              void* d_out, int out_size, void* d_ws, size_t ws_size,
                              hipStream_t stream) {
  (void)in_sizes; (void)n_in; (void)out_size; (void)ws_size;
  const float* x    = (const float*)d_in[0];
  const float* W_ih = (const float*)d_in[1];
  const float* W_hh = (const float*)d_in[2];
  const float* b_ih = (const float*)d_in[3];
  const float* b_hh = (const float*)d_in[4];
  const float* Wq   = (const float*)d_in[5];
  const float* bq   = (const float*)d_in[6];
  const float* Wa   = (const float*)d_in[7];
  const float* ba   = (const float*)d_in[8];
  const float* Wc   = (const float*)d_in[9];
  const float* bc   = (const float*)d_in[10];
  const float* Wo   = (const float*)d_in[11];
  const float* bo   = (const float*)d_in[12];
  const float* keys = (const float*)d_in[13];
  const float* vals = (const float*)d_in[14];

  float* ws      = (float*)d_ws;
  float* xg      = ws + 0;
  float* h_seq   = ws + 2097152;
  float* qbuf    = ws + 2623488;
  float* invn    = ws + 2754560;
  float* mem_pre = ws + 2854560;
  float* mem_cmb = ws + 2985632;
  float* pvals   = ws + 3116704;
  int*   pidx    = (int*)(ws + 3313312);
  unsigned* qbf  = (unsigned*)(ws + 3509920);
  unsigned* kbf  = (unsigned*)(ws + 3575456);

  init_k<<<2056, 256, 0, stream>>>(h_seq);
  gemm_k<0><<<dim3(16, 32), 256, 0, stream>>>(x, nullptr, W_ih, b_ih, b_hh, xg,
                                              1024, 2048, 256);
  convk_k<<<25000, 256, 0, stream>>>(keys, invn, kbf);
  lstm_k<<<64, 1024, 0, stream>>>(xg, W_hh, h_seq);
  gemm_k<1><<<dim3(16, 2), 256, 0, stream>>>(h_seq, nullptr, Wq, bq, nullptr,
                                             qbuf, 1024, 128, 512);
  qnorm_k<<<256, 256, 0, stream>>>(qbuf, qbf);
  simsmfma_k<<<dim3(16, 32), 256, 0, stream>>>(qbf, kbf, pvals, pidx);
  merge_rescore_k<<<256, 256, 0, stream>>>(pvals, pidx, qbuf, keys, invn, vals,
                                           Wa, ba, mem_pre);
  gemm_k<0><<<dim3(16, 2), 256, 0, stream>>>(mem_pre, nullptr, Wc, bc, nullptr,
                                             mem_cmb, 1024, 128, 128);
  gemm_k<2><<<dim3(16, 4), 256, 0, stream>>>(h_seq, mem_cmb, Wo, bo, nullptr,
                                             (float*)d_out, 1024, 256, 640);
}

// Round 5
// 1158.628 us; speedup vs baseline: 15.4625x; 1.0442x over previous
//
#include <hip/hip_runtime.h>
#include <math.h>

#define INF __builtin_inff()
#define SENT 0x7FA00000u
#define IMAX 0x7fffffff

typedef __attribute__((ext_vector_type(8))) short bhalf8;
typedef __attribute__((ext_vector_type(4))) float f32x4;

// ---------------- workspace layout (float offsets) ----------------
// xg      : 0        (1024 x 2048)   sentinel-initialized, data-as-flag
// h_seq   : 2097152  (257 x 4 x 512) sentinel-initialized, data-as-flag
// qbuf    : 2623488  (1024 x 128)  fp32 normalized q
// invn    : 2754560  (100000)
// mem_pre : 2854560  (1024 x 128)
// mem_cmb : 2985632  (1024 x 128)
// pvals   : 3116704  (32 x 1024 x 6)
// pidx    : 3313312  (32 x 1024 x 6) int
// qbf     : 3509920  (1024 x 64 uint)   bf16x2 normalized q
// kbf     : 3575456  (100000 x 64 uint) bf16x2 unit-scaled keys

__device__ __forceinline__ void ins3b(float& v0, int& i0, float& v1, int& i1,
                                      float& v2, int& i2, float nv, int ni) {
  bool b0 = (nv > v0) || (nv == v0 && ni < i0);
  bool b1 = (nv > v1) || (nv == v1 && ni < i1);
  bool b2 = (nv > v2) || (nv == v2 && ni < i2);
  v2 = b1 ? v1 : (b2 ? nv : v2);
  i2 = b1 ? i1 : (b2 ? ni : i2);
  v1 = b0 ? v0 : (b1 ? nv : v1);
  i1 = b0 ? i0 : (b1 ? ni : i1);
  v0 = b0 ? nv : v0;
  i0 = b0 ? ni : i0;
}

__device__ __forceinline__ unsigned short f2bf(float x) {  // RNE
  unsigned u = __float_as_uint(x);
  return (unsigned short)((u + 0x7FFFu + ((u >> 16) & 1u)) >> 16);
}

// sentinel-init xg (all) + h_seq (t=0 slab -> 0, rest sentinel); contiguous.
__global__ void init_k(float* __restrict__ base) {
  int t = blockIdx.x * 256 + threadIdx.x;   // grid 10248 x 256
  if (t < 2623488) {
    bool zero = (t >= 2097152) && (t < 2097152 + 2048);
    base[t] = zero ? 0.f : __uint_as_float(SENT);
  }
}

// ---------------- generic tiled GEMM: C(MxN) = A(MxK) @ B(NxK)^T + bias ----
// AMODE 1: A row r=(b*256+s) -> h_seq[(s+1)*4+b].  AMODE 0 plain.  AMODE 2:
// concat [h | A2(1024x128)], K=640.
template<int AMODE>
__global__ __launch_bounds__(256) void gemm_k(
    const float* __restrict__ A, const float* __restrict__ A2,
    const float* __restrict__ Bw, const float* __restrict__ b1,
    const float* __restrict__ b2, float* __restrict__ C,
    int M, int N, int K) {
  __shared__ float4 As4[64][16];
  __shared__ float4 Bs4[64][16];
  const int t = threadIdx.x;
  const int tx = t & 15, ty = t >> 4;
  const int brow = blockIdx.x * 64, bcol = blockIdx.y * 64;
  const int srow = t >> 2, scb = t & 3;
  float acc[4][4] = {};
  for (int kt = 0; kt < K; kt += 64) {
#pragma unroll
    for (int u = 0; u < 4; ++u) {
      int c = scb + 4 * u;
      int gk = kt + c * 4;
      int gr = brow + srow;
      const float* ap;
      if (AMODE == 0) {
        ap = A + (size_t)gr * K + gk;
      } else {
        int b = gr >> 8, s = gr & 255;
        const float* hrow = A + ((size_t)(s + 1) * 4 + b) * 512;
        if (AMODE == 1) ap = hrow + gk;
        else ap = (gk < 512) ? (hrow + gk) : (A2 + (size_t)gr * 128 + (gk - 512));
      }
      As4[srow][c ^ (srow & 15)] = *(const float4*)ap;
      Bs4[srow][c ^ (srow & 15)] = *(const float4*)(Bw + (size_t)(bcol + srow) * K + gk);
    }
    __syncthreads();
#pragma unroll
    for (int d4 = 0; d4 < 16; ++d4) {
      float4 av[4], bv[4];
#pragma unroll
      for (int i = 0; i < 4; ++i) av[i] = As4[ty * 4 + i][d4 ^ ((ty * 4 + i) & 15)];
#pragma unroll
      for (int j = 0; j < 4; ++j) bv[j] = Bs4[tx * 4 + j][d4 ^ ((tx * 4 + j) & 15)];
#pragma unroll
      for (int i = 0; i < 4; ++i)
#pragma unroll
        for (int j = 0; j < 4; ++j)
          acc[i][j] += av[i].x * bv[j].x + av[i].y * bv[j].y +
                       av[i].z * bv[j].z + av[i].w * bv[j].w;
    }
    __syncthreads();
  }
#pragma unroll
  for (int i = 0; i < 4; ++i) {
    int r = brow + ty * 4 + i;
#pragma unroll
    for (int j = 0; j < 4; ++j) {
      int n = bcol + tx * 4 + j;
      float bias = b1[n];
      if (b2) bias += b2[n];
      C[(size_t)r * N + n] = acc[i][j] + bias;
    }
  }
}

// ---------------- fused front: LSTM (0..63) | xg-GEMM (64..575) | key conv -
// LSTM: 16 blocks/batch, 512 thr, thread=(unit uu, li): all 4 gates,
// w[4][32] fp32. One barrier/step (h_lds double-buffered). h and xg are
// data-as-flag (NaN sentinel) via relaxed agent-scope atomics.
__global__ __launch_bounds__(512, 2) void fused_front(
    const float* __restrict__ x, const float* __restrict__ W_ih,
    const float* __restrict__ b_ih, const float* __restrict__ b_hh,
    const float* __restrict__ W_hh, const float* __restrict__ keys,
    float* __restrict__ xg, float* __restrict__ h_seq,
    float* __restrict__ invn, unsigned* __restrict__ kbf) {
  __shared__ alignas(16) unsigned char smem[32768];
  const int bid = blockIdx.x;
  const int t = threadIdx.x;

  if (bid < 64) {
    // ---------------- LSTM ----------------
    const int batch = bid >> 4;
    const int ub = bid & 15;
    const int uu = t >> 4;             // 0..31 local unit
    const int li = t & 15;             // 16 lanes/unit, 32 dims each
    const int unit = ub * 32 + uu;
    float* h_lds = (float*)smem;       // [2][576] double-buffered

    float w[4][32];
#pragma unroll
    for (int g = 0; g < 4; ++g) {
      const float* wr = W_hh + (size_t)(g * 512 + unit) * 512 + li * 32;
#pragma unroll
      for (int j = 0; j < 32; j += 4) {
        float4 v = *(const float4*)(wr + j);
        w[g][j] = v.x; w[g][j + 1] = v.y; w[g][j + 2] = v.z; w[g][j + 3] = v.w;
      }
    }
    float c = 0.f;
    float xgv[4];
    {
      float* xq = xg + (size_t)(batch * 256) * 2048 + unit;
      bool again;
      do {
        again = false;
#pragma unroll
        for (int g = 0; g < 4; ++g)
          xgv[g] = __hip_atomic_load(xq + g * 512, __ATOMIC_RELAXED,
                                     __HIP_MEMORY_SCOPE_AGENT);
#pragma unroll
        for (int g = 0; g < 4; ++g)
          again |= (__float_as_uint(xgv[g]) == SENT);
      } while (again);
    }

    for (int step = 0; step < 256; ++step) {
      {
        float* hp = h_seq + ((size_t)step * 4 + batch) * 512 + t;
        float hv;
        do {
          hv = __hip_atomic_load(hp, __ATOMIC_RELAXED, __HIP_MEMORY_SCOPE_AGENT);
        } while (__float_as_uint(hv) == SENT);
        h_lds[(step & 1) * 576 + (t >> 5) * 36 + (t & 31)] = hv;
      }
      __syncthreads();
      const float* hb = h_lds + (step & 1) * 576 + li * 36;
      float a0 = 0.f, a1 = 0.f, a2 = 0.f, a3 = 0.f;
#pragma unroll
      for (int j = 0; j < 32; j += 4) {
        float4 hv = *(const float4*)(hb + j);
        a0 += w[0][j] * hv.x + w[0][j + 1] * hv.y + w[0][j + 2] * hv.z + w[0][j + 3] * hv.w;
        a1 += w[1][j] * hv.x + w[1][j + 1] * hv.y + w[1][j + 2] * hv.z + w[1][j + 3] * hv.w;
        a2 += w[2][j] * hv.x + w[2][j + 1] * hv.y + w[2][j + 2] * hv.z + w[2][j + 3] * hv.w;
        a3 += w[3][j] * hv.x + w[3][j + 1] * hv.y + w[3][j + 2] * hv.z + w[3][j + 3] * hv.w;
      }
#pragma unroll
      for (int m = 1; m < 16; m <<= 1) {
        a0 += __shfl_xor(a0, m, 64); a1 += __shfl_xor(a1, m, 64);
        a2 += __shfl_xor(a2, m, 64); a3 += __shfl_xor(a3, m, 64);
      }
      a0 += xgv[0]; a1 += xgv[1]; a2 += xgv[2]; a3 += xgv[3];
      float i_ = 1.f / (1.f + expf(-a0));
      float f_ = 1.f / (1.f + expf(-a1));
      float g_ = tanhf(a2);
      float o_ = 1.f / (1.f + expf(-a3));
      c = f_ * c + i_ * g_;
      float h = o_ * tanhf(c);
      if (li == 0)
        __hip_atomic_store(h_seq + ((size_t)(step + 1) * 4 + batch) * 512 + unit,
                           h, __ATOMIC_RELAXED, __HIP_MEMORY_SCOPE_AGENT);
      if (step < 255) {                // prefetch next xg (normally instant)
        float* xq = xg + (size_t)(batch * 256 + step + 1) * 2048 + unit;
        bool again;
        do {
          again = false;
#pragma unroll
          for (int g = 0; g < 4; ++g)
            xgv[g] = __hip_atomic_load(xq + g * 512, __ATOMIC_RELAXED,
                                       __HIP_MEMORY_SCOPE_AGENT);
#pragma unroll
          for (int g = 0; g < 4; ++g)
            again |= (__float_as_uint(xgv[g]) == SENT);
        } while (again);
      }
    }
  } else if (bid < 576) {
    // ---------------- xg GEMM: xg = x @ W_ih^T + (b_ih+b_hh) -------------
    // tile order: step-quarter q ascending so early LSTM rows come first
    const int g = bid - 64;
    const int q = g >> 7;              // 0..3
    const int b = (g >> 5) & 3;        // batch
    const int col = g & 31;
    const int brow = (b * 4 + q) * 64, bcol = col * 64;
    float4* As4 = (float4*)smem;                 // [64][16]
    float4* Bs4 = (float4*)(smem + 16384);       // [64][16]
    const int tx = t & 15, ty = (t >> 4) & 15;
    const int srow = (t & 255) >> 2, scb = t & 3;
    float acc[4][4] = {};
    for (int kt = 0; kt < 256; kt += 64) {
      if (t < 256) {
#pragma unroll
        for (int u = 0; u < 4; ++u) {
          int cc = scb + 4 * u;
          int gk = kt + cc * 4;
          As4[srow * 16 + (cc ^ (srow & 15))] =
              *(const float4*)(x + (size_t)(brow + srow) * 256 + gk);
          Bs4[srow * 16 + (cc ^ (srow & 15))] =
              *(const float4*)(W_ih + (size_t)(bcol + srow) * 256 + gk);
        }
      }
      __syncthreads();
      if (t < 256) {
#pragma unroll
        for (int d4 = 0; d4 < 16; ++d4) {
          float4 av[4], bv[4];
#pragma unroll
          for (int i = 0; i < 4; ++i)
            av[i] = As4[(ty * 4 + i) * 16 + (d4 ^ ((ty * 4 + i) & 15))];
#pragma unroll
          for (int j = 0; j < 4; ++j)
            bv[j] = Bs4[(tx * 4 + j) * 16 + (d4 ^ ((tx * 4 + j) & 15))];
#pragma unroll
          for (int i = 0; i < 4; ++i)
#pragma unroll
            for (int j = 0; j < 4; ++j)
              acc[i][j] += av[i].x * bv[j].x + av[i].y * bv[j].y +
                           av[i].z * bv[j].z + av[i].w * bv[j].w;
        }
      }
      __syncthreads();
    }
    if (t < 256) {
#pragma unroll
      for (int i = 0; i < 4; ++i) {
        int r = brow + ty * 4 + i;
#pragma unroll
        for (int j = 0; j < 4; ++j) {
          int n = bcol + tx * 4 + j;
          __hip_atomic_store(xg + (size_t)r * 2048 + n,
                             acc[i][j] + b_ih[n] + b_hh[n],
                             __ATOMIC_RELAXED, __HIP_MEMORY_SCOPE_AGENT);
        }
      }
    }
  } else {
    // ---------------- key conversion: invn + unit-scaled bf16 ------------
    const int rb = (bid - 576) * 256;
    const int wv = t >> 6, lane = t & 63;
    for (int p = 0; p < 32; ++p) {
      int r = rb + p * 8 + wv;
      if (r < 100000) {
        float2 v = *(const float2*)(keys + (size_t)r * 128 + lane * 2);
        float ss = v.x * v.x + v.y * v.y;
#pragma unroll
        for (int m = 1; m < 64; m <<= 1) ss += __shfl_xor(ss, m, 64);
        float inv = 1.f / fmaxf(sqrtf(ss), 1e-12f);
        if (lane == 0) invn[r] = inv;
        kbf[(size_t)r * 64 + lane] =
            (unsigned)f2bf(v.x * inv) | ((unsigned)f2bf(v.y * inv) << 16);
      }
    }
  }
}

// ---------------- q row-normalize + bf16 pack ------------------------------
__global__ __launch_bounds__(256) void qnorm_k(float* __restrict__ q,
                                               unsigned* __restrict__ qbf) {
  int wv = threadIdx.x >> 6, lane = threadIdx.x & 63;
  int r = blockIdx.x * 4 + wv;
  float2 v = *(float2*)(q + (size_t)r * 128 + lane * 2);
  float ss = v.x * v.x + v.y * v.y;
#pragma unroll
  for (int m = 1; m < 64; m <<= 1) ss += __shfl_xor(ss, m, 64);
  float inv = 1.f / fmaxf(sqrtf(ss), 1e-12f);
  v.x *= inv; v.y *= inv;
  *(float2*)(q + (size_t)r * 128 + lane * 2) = v;
  qbf[(size_t)r * 64 + lane] = (unsigned)f2bf(v.x) | ((unsigned)f2bf(v.y) << 16);
}

// stage one 64x128-bf16 tile: LINEAR LDS dest (global_load_lds), source
// pre-swizzled so readers XOR-deswizzle.
__device__ __forceinline__ void stage_tile(unsigned short* dst,
                                           const unsigned* src,
                                           int baserow, int maxrow,
                                           int w, int l) {
#pragma unroll
  for (int u = 0; u < 4; ++u) {
    int s = u * 256 + w * 64 + l;
    int row = s >> 4, cc = s & 15;
    int gr = baserow + row; gr = gr > maxrow ? maxrow : gr;
    const unsigned* sp = src + (size_t)gr * 64 + ((cc ^ (row & 7)) << 2);
    __builtin_amdgcn_global_load_lds(
        (const __attribute__((address_space(1))) unsigned*)sp,
        (__attribute__((address_space(3))) unsigned*)(dst + (size_t)(u * 256 + w * 64) * 8),
        16, 0, 0);
  }
}

// ---------------- bf16 MFMA sims + per-chunk top-6 candidates --------------
__global__ __launch_bounds__(256, 2) void simsmfma_k(
    const unsigned* __restrict__ qbf, const unsigned* __restrict__ kbf,
    float* __restrict__ pvals, int* __restrict__ pidx) {
  const int qt = blockIdx.x, ch = blockIdx.y;
  const int kbeg = ch * 3125, klim = kbeg + 3125;   // 49 steps of 64
  const int t = threadIdx.x, l = t & 63, w = t >> 6;
  __shared__ alignas(16) unsigned short ks0[8192];
  __shared__ alignas(16) unsigned short ks1[8192];

  stage_tile(ks1, qbf, qt * 64, 1023, w, l);
  __syncthreads();
  bhalf8 afrag[4];
  {
    int row = w * 16 + (l & 15);
#pragma unroll
    for (int db = 0; db < 4; ++db) {
      int cslot = db * 4 + (l >> 4);
      afrag[db] = *(const bhalf8*)&ks1[(size_t)(row * 16 + (cslot ^ (row & 7))) * 8];
    }
  }
  stage_tile(ks0, kbf, kbeg, klim - 1, w, l);
  __syncthreads();

  float tv0[4], tv1[4], tv2[4]; int ti0[4], ti1[4], ti2[4];
#pragma unroll
  for (int r = 0; r < 4; ++r) {
    tv0[r] = tv1[r] = tv2[r] = -INF;
    ti0[r] = ti1[r] = ti2[r] = IMAX;
  }

  for (int s = 0; s < 49; ++s) {
    unsigned short* cur = (s & 1) ? ks1 : ks0;
    unsigned short* nxt = (s & 1) ? ks0 : ks1;
    if (s < 48) stage_tile(nxt, kbf, kbeg + (s + 1) * 64, klim - 1, w, l);
    int k0 = kbeg + s * 64;

    f32x4 ac0 = {0,0,0,0}, ac1 = {0,0,0,0}, ac2 = {0,0,0,0}, ac3 = {0,0,0,0};
    const int r0 = l & 15;
#pragma unroll
    for (int db = 0; db < 4; ++db) {
      int swz = (db * 4 + (l >> 4)) ^ (r0 & 7);
      bhalf8 b0 = *(const bhalf8*)&cur[(size_t)((r0     ) * 16 + swz) * 8];
      bhalf8 b1 = *(const bhalf8*)&cur[(size_t)((r0 + 16) * 16 + swz) * 8];
      bhalf8 b2 = *(const bhalf8*)&cur[(size_t)((r0 + 32) * 16 + swz) * 8];
      bhalf8 b3 = *(const bhalf8*)&cur[(size_t)((r0 + 48) * 16 + swz) * 8];
      ac0 = __builtin_amdgcn_mfma_f32_16x16x32_bf16(afrag[db], b0, ac0, 0, 0, 0);
      ac1 = __builtin_amdgcn_mfma_f32_16x16x32_bf16(afrag[db], b1, ac1, 0, 0, 0);
      ac2 = __builtin_amdgcn_mfma_f32_16x16x32_bf16(afrag[db], b2, ac2, 0, 0, 0);
      ac3 = __builtin_amdgcn_mfma_f32_16x16x32_bf16(afrag[db], b3, ac3, 0, 0, 0);
    }
#pragma unroll
    for (int nt = 0; nt < 4; ++nt) {
      f32x4 a = (nt == 0) ? ac0 : (nt == 1) ? ac1 : (nt == 2) ? ac2 : ac3;
      int gk = k0 + nt * 16 + (l & 15);
      bool ok = gk < klim;
#pragma unroll
      for (int r = 0; r < 4; ++r) {
        float v = ok ? a[r] : -INF;
        ins3b(tv0[r], ti0[r], tv1[r], ti1[r], tv2[r], ti2[r], v, gk);
      }
    }
    __syncthreads();
  }

#pragma unroll
  for (int r = 0; r < 4; ++r) {
    float c0 = tv0[r], c1 = tv1[r], c2 = tv2[r];
    int j0 = ti0[r], j1 = ti1[r], j2 = ti2[r];
    int qrow = qt * 64 + w * 16 + (l >> 4) * 4 + r;
    size_t ob = ((size_t)ch * 1024 + qrow) * 6;
#pragma unroll
    for (int e = 0; e < 6; ++e) {
      float mv = c0; int mi = j0;
#pragma unroll
      for (int m = 1; m < 16; m <<= 1) {
        float o = __shfl_xor(mv, m, 64); int oi = __shfl_xor(mi, m, 64);
        bool tk = (o > mv) || (o == mv && oi < mi);
        mv = tk ? o : mv; mi = tk ? oi : mi;
      }
      if (mi == j0) { c0 = c1; j0 = j1; c1 = c2; j1 = j2; c2 = -INF; j2 = IMAX; }
      if ((l & 15) == 0) { pvals[ob + e] = mv; pidx[ob + e] = mi; }
    }
  }
}

// ---------------- merge chunks + fp32 rescore + attention ------------------
__global__ __launch_bounds__(256) void merge_rescore_k(
    const float* __restrict__ pvals, const int* __restrict__ pidx,
    const float* __restrict__ qf, const float* __restrict__ keys,
    const float* __restrict__ invn, const float* __restrict__ mvals,
    const float* __restrict__ Wa, const float* __restrict__ ba,
    float* __restrict__ mem_pre) {
  int wv = threadIdx.x >> 6, l = threadIdx.x & 63;
  int qr = blockIdx.x * 4 + wv;
  float h0 = -INF, h1 = -INF, h2 = -INF;
  int g0 = IMAX, g1 = IMAX, g2 = IMAX;
#pragma unroll
  for (int e = 0; e < 3; ++e) {
    int c = l * 3 + e;
    size_t base = ((size_t)(c / 6) * 1024 + qr) * 6 + (c % 6);
    ins3b(h0, g0, h1, g1, h2, g2, pvals[base], pidx[base]);
  }
  float sc[8]; int si[8];
#pragma unroll
  for (int e = 0; e < 8; ++e) {
    float mv = h0; int mi = g0;
#pragma unroll
    for (int m = 1; m < 64; m <<= 1) {
      float o = __shfl_xor(mv, m, 64); int oi = __shfl_xor(mi, m, 64);
      bool tk = (o > mv) || (o == mv && oi < mi);
      mv = tk ? o : mv; mi = tk ? oi : mi;
    }
    sc[e] = mv; si[e] = mi;
    if (mi == g0) { h0 = h1; g0 = g1; h1 = h2; g1 = g2; h2 = -INF; g2 = IMAX; }
  }
  int d = l * 2;
  float q0 = qf[(size_t)qr * 128 + d], q1 = qf[(size_t)qr * 128 + d + 1];
  float ex[8];
#pragma unroll
  for (int e = 0; e < 8; ++e) {
    int k = si[e];
    float p = q0 * keys[(size_t)k * 128 + d] + q1 * keys[(size_t)k * 128 + d + 1];
#pragma unroll
    for (int m = 1; m < 64; m <<= 1) p += __shfl_xor(p, m, 64);
    ex[e] = p * invn[k];
  }
  float v0 = -INF, v1 = -INF, v2 = -INF;
  int i0 = IMAX, i1 = IMAX, i2 = IMAX;
#pragma unroll
  for (int e = 0; e < 8; ++e) ins3b(v0, i0, v1, i1, v2, i2, ex[e], si[e]);
  float r00 = mvals[(size_t)i0 * 128 + d], r01 = mvals[(size_t)i0 * 128 + d + 1];
  float r10 = mvals[(size_t)i1 * 128 + d], r11 = mvals[(size_t)i1 * 128 + d + 1];
  float r20 = mvals[(size_t)i2 * 128 + d], r21 = mvals[(size_t)i2 * 128 + d + 1];
  float wa0 = Wa[d], wa1 = Wa[d + 1];
  float p0 = wa0 * r00 + wa1 * r01;
  float p1 = wa0 * r10 + wa1 * r11;
  float p2 = wa0 * r20 + wa1 * r21;
#pragma unroll
  for (int m = 1; m < 64; m <<= 1) {
    p0 += __shfl_xor(p0, m, 64);
    p1 += __shfl_xor(p1, m, 64);
    p2 += __shfl_xor(p2, m, 64);
  }
  float bav = ba[0];
  float l0 = p0 + bav, l1 = p1 + bav, l2 = p2 + bav;
  float mx = fmaxf(l0, fmaxf(l1, l2));
  float e0 = expf(l0 - mx), e1 = expf(l1 - mx), e2 = expf(l2 - mx);
  float s = e0 + e1 + e2;
  float a0 = e0 / s, a1 = e1 / s, a2 = e2 / s;
  mem_pre[(size_t)qr * 128 + d]     = a0 * r00 + a1 * r10 + a2 * r20;
  mem_pre[(size_t)qr * 128 + d + 1] = a0 * r01 + a1 * r11 + a2 * r21;
}

// ---------------------------------------------------------------------------
extern "C" void kernel_launch(void* const* d_in, const int* in_sizes, int n_in,
                              void* d_out, int out_size, void* d_ws, size_t ws_size,
                              hipStream_t stream) {
  (void)in_sizes; (void)n_in; (void)out_size; (void)ws_size;
  const float* x    = (const float*)d_in[0];
  const float* W_ih = (const float*)d_in[1];
  const float* W_hh = (const float*)d_in[2];
  const float* b_ih = (const float*)d_in[3];
  const float* b_hh = (const float*)d_in[4];
  const float* Wq   = (const float*)d_in[5];
  const float* bq   = (const float*)d_in[6];
  const float* Wa   = (const float*)d_in[7];
  const float* ba   = (const float*)d_in[8];
  const float* Wc   = (const float*)d_in[9];
  const float* bc   = (const float*)d_in[10];
  const float* Wo   = (const float*)d_in[11];
  const float* bo   = (const float*)d_in[12];
  const float* keys = (const float*)d_in[13];
  const float* vals = (const float*)d_in[14];

  float* ws      = (float*)d_ws;
  float* xg      = ws + 0;
  float* h_seq   = ws + 2097152;
  float* qbuf    = ws + 2623488;
  float* invn    = ws + 2754560;
  float* mem_pre = ws + 2854560;
  float* mem_cmb = ws + 2985632;
  float* pvals   = ws + 3116704;
  int*   pidx    = (int*)(ws + 3313312);
  unsigned* qbf  = (unsigned*)(ws + 3509920);
  unsigned* kbf  = (unsigned*)(ws + 3575456);

  init_k<<<10248, 256, 0, stream>>>(ws);
  fused_front<<<967, 512, 0, stream>>>(x, W_ih, b_ih, b_hh, W_hh, keys,
                                       xg, h_seq, invn, kbf);
  gemm_k<1><<<dim3(16, 2), 256, 0, stream>>>(h_seq, nullptr, Wq, bq, nullptr,
                                             qbuf, 1024, 128, 512);
  qnorm_k<<<256, 256, 0, stream>>>(qbuf, qbf);
  simsmfma_k<<<dim3(16, 32), 256, 0, stream>>>(qbf, kbf, pvals, pidx);
  merge_rescore_k<<<256, 256, 0, stream>>>(pvals, pidx, qbuf, keys, invn, vals,
                                           Wa, ba, mem_pre);
  gemm_k<0><<<dim3(16, 2), 256, 0, stream>>>(mem_pre, nullptr, Wc, bc, nullptr,
                                             mem_cmb, 1024, 128, 128);
  gemm_k<2><<<dim3(16, 4), 256, 0, stream>>>(h_seq, mem_cmb, Wo, bo, nullptr,
                                             (float*)d_out, 1024, 256, 640);
}

// Round 6
// 1132.861 us; speedup vs baseline: 15.8142x; 1.0227x over previous
//
#include <hip/hip_runtime.h>
#include <math.h>

#define INF __builtin_inff()
#define SENT 0x7FA00000u
#define IMAX 0x7fffffff

typedef __attribute__((ext_vector_type(8))) short bhalf8;
typedef __attribute__((ext_vector_type(4))) float f32x4;

// ---------------- workspace layout (float offsets) ----------------
// xg      : 0        (1024 x 2048)   plain GEMM output (release-flagged)
// h_seq   : 2097152  (257 x 4 x 512) sentinel-initialized, data-as-flag
// qbuf    : 2623488  (1024 x 128)  fp32 normalized q
// invn    : 2754560  (100000)
// mem_pre : 2854560  (1024 x 128)
// mem_cmb : 2985632  (1024 x 128)
// pvals   : 3116704  (32 x 1024 x 6)   [0..15] alias: xg quarter flags
// pidx    : 3313312  (32 x 1024 x 6) int
// qbf     : 3509920  (1024 x 64 uint)   bf16x2 normalized q
// kbf     : 3575456  (100000 x 64 uint) bf16x2 unit-scaled keys

__device__ __forceinline__ void ins3b(float& v0, int& i0, float& v1, int& i1,
                                      float& v2, int& i2, float nv, int ni) {
  bool b0 = (nv > v0) || (nv == v0 && ni < i0);
  bool b1 = (nv > v1) || (nv == v1 && ni < i1);
  bool b2 = (nv > v2) || (nv == v2 && ni < i2);
  v2 = b1 ? v1 : (b2 ? nv : v2);
  i2 = b1 ? i1 : (b2 ? ni : i2);
  v1 = b0 ? v0 : (b1 ? nv : v1);
  i1 = b0 ? i0 : (b1 ? ni : i1);
  v0 = b0 ? nv : v0;
  i0 = b0 ? ni : i0;
}

__device__ __forceinline__ unsigned short f2bf(float x) {  // RNE
  unsigned u = __float_as_uint(x);
  return (unsigned short)((u + 0x7FFFu + ((u >> 16) & 1u)) >> 16);
}

// h_seq: t=0 slab -> 0, rest sentinel. xg flags -> 0.
__global__ void init_k(float* __restrict__ h_seq, unsigned* __restrict__ flags) {
  int t = blockIdx.x * 256 + threadIdx.x;   // grid 2056 x 256 = 526336
  if (t < 526336) h_seq[t] = (t < 2048) ? 0.f : __uint_as_float(SENT);
  if (t < 16) flags[t] = 0u;
}

// ---------------- generic tiled GEMM: C(MxN) = A(MxK) @ B(NxK)^T + bias ----
// AMODE 1: A row r=(b*256+s) -> h_seq[(s+1)*4+b].  AMODE 0 plain.  AMODE 2:
// concat [h | A2(1024x128)], K=640.
template<int AMODE>
__global__ __launch_bounds__(256) void gemm_k(
    const float* __restrict__ A, const float* __restrict__ A2,
    const float* __restrict__ Bw, const float* __restrict__ b1,
    const float* __restrict__ b2, float* __restrict__ C,
    int M, int N, int K) {
  __shared__ float4 As4[64][16];
  __shared__ float4 Bs4[64][16];
  const int t = threadIdx.x;
  const int tx = t & 15, ty = t >> 4;
  const int brow = blockIdx.x * 64, bcol = blockIdx.y * 64;
  const int srow = t >> 2, scb = t & 3;
  float acc[4][4] = {};
  for (int kt = 0; kt < K; kt += 64) {
#pragma unroll
    for (int u = 0; u < 4; ++u) {
      int c = scb + 4 * u;
      int gk = kt + c * 4;
      int gr = brow + srow;
      const float* ap;
      if (AMODE == 0) {
        ap = A + (size_t)gr * K + gk;
      } else {
        int b = gr >> 8, s = gr & 255;
        const float* hrow = A + ((size_t)(s + 1) * 4 + b) * 512;
        if (AMODE == 1) ap = hrow + gk;
        else ap = (gk < 512) ? (hrow + gk) : (A2 + (size_t)gr * 128 + (gk - 512));
      }
      As4[srow][c ^ (srow & 15)] = *(const float4*)ap;
      Bs4[srow][c ^ (srow & 15)] = *(const float4*)(Bw + (size_t)(bcol + srow) * K + gk);
    }
    __syncthreads();
#pragma unroll
    for (int d4 = 0; d4 < 16; ++d4) {
      float4 av[4], bv[4];
#pragma unroll
      for (int i = 0; i < 4; ++i) av[i] = As4[ty * 4 + i][d4 ^ ((ty * 4 + i) & 15)];
#pragma unroll
      for (int j = 0; j < 4; ++j) bv[j] = Bs4[tx * 4 + j][d4 ^ ((tx * 4 + j) & 15)];
#pragma unroll
      for (int i = 0; i < 4; ++i)
#pragma unroll
        for (int j = 0; j < 4; ++j)
          acc[i][j] += av[i].x * bv[j].x + av[i].y * bv[j].y +
                       av[i].z * bv[j].z + av[i].w * bv[j].w;
    }
    __syncthreads();
  }
#pragma unroll
  for (int i = 0; i < 4; ++i) {
    int r = brow + ty * 4 + i;
#pragma unroll
    for (int j = 0; j < 4; ++j) {
      int n = bcol + tx * 4 + j;
      float bias = b1[n];
      if (b2) bias += b2[n];
      C[(size_t)r * N + n] = acc[i][j] + bias;
    }
  }
}

// ---------------- fused front: LSTM (0..63) | xg-GEMM (64..575) | key conv -
// LSTM: 16 blocks/batch, 512 thr, thread=(unit uu, li): all 4 gates.
// h is data-as-flag (NaN sentinel, relaxed agent atomics) — the only per-step
// L3 round trip. xg is release/acquire-flagged per (batch, quarter): plain
// cached loads, prefetched 2 steps ahead (off the critical path).
__global__ __launch_bounds__(512, 2) void fused_front(
    const float* __restrict__ x, const float* __restrict__ W_ih,
    const float* __restrict__ b_ih, const float* __restrict__ b_hh,
    const float* __restrict__ W_hh, const float* __restrict__ keys,
    float* __restrict__ xg, float* __restrict__ h_seq,
    float* __restrict__ invn, unsigned* __restrict__ kbf,
    unsigned* __restrict__ xgflag) {
  __shared__ alignas(16) unsigned char smem[32768];
  const int bid = blockIdx.x;
  const int t = threadIdx.x;

  if (bid < 64) {
    // ---------------- LSTM ----------------
    const int batch = bid >> 4;
    const int ub = bid & 15;
    const int uu = t >> 4;             // 0..31 local unit
    const int li = t & 15;             // 16 lanes/unit, 32 dims each
    const int unit = ub * 32 + uu;
    float* h_lds = (float*)smem;       // [2][576] double-buffered

    float w[4][32];
#pragma unroll
    for (int g = 0; g < 4; ++g) {
      const float* wr = W_hh + (size_t)(g * 512 + unit) * 512 + li * 32;
#pragma unroll
      for (int j = 0; j < 32; j += 4) {
        float4 v = *(const float4*)(wr + j);
        w[g][j] = v.x; w[g][j + 1] = v.y; w[g][j + 2] = v.z; w[g][j + 3] = v.w;
      }
    }
    float c = 0.f;
    // wait for xg quarter 0 (relaxed spin, then one acquire for the fence)
    {
      const unsigned* f0 = xgflag + batch * 4;
      while (__hip_atomic_load(f0, __ATOMIC_RELAXED, __HIP_MEMORY_SCOPE_AGENT) < 32u) {}
      (void)__hip_atomic_load(f0, __ATOMIC_ACQUIRE, __HIP_MEMORY_SCOPE_AGENT);
    }
    float xcur[4], xnxt[4];
    {
      const float* xq = xg + (size_t)(batch * 256) * 2048 + unit;
#pragma unroll
      for (int g = 0; g < 4; ++g) xcur[g] = xq[g * 512];
#pragma unroll
      for (int g = 0; g < 4; ++g) xnxt[g] = xq[2048 + g * 512];
    }

    for (int step = 0; step < 256; ++step) {
      {
        float* hp = h_seq + ((size_t)step * 4 + batch) * 512 + t;
        float hv;
        do {
          hv = __hip_atomic_load(hp, __ATOMIC_RELAXED, __HIP_MEMORY_SCOPE_AGENT);
        } while (__float_as_uint(hv) == SENT);
        h_lds[(step & 1) * 576 + (t >> 5) * 36 + (t & 31)] = hv;
      }
      __syncthreads();
      const float* hb = h_lds + (step & 1) * 576 + li * 36;
      float a0 = 0.f, a1 = 0.f, a2 = 0.f, a3 = 0.f;
#pragma unroll
      for (int j = 0; j < 32; j += 4) {
        float4 hv = *(const float4*)(hb + j);
        a0 += w[0][j] * hv.x + w[0][j + 1] * hv.y + w[0][j + 2] * hv.z + w[0][j + 3] * hv.w;
        a1 += w[1][j] * hv.x + w[1][j + 1] * hv.y + w[1][j + 2] * hv.z + w[1][j + 3] * hv.w;
        a2 += w[2][j] * hv.x + w[2][j + 1] * hv.y + w[2][j + 2] * hv.z + w[2][j + 3] * hv.w;
        a3 += w[3][j] * hv.x + w[3][j + 1] * hv.y + w[3][j + 2] * hv.z + w[3][j + 3] * hv.w;
      }
#pragma unroll
      for (int m = 1; m < 16; m <<= 1) {
        a0 += __shfl_xor(a0, m, 64); a1 += __shfl_xor(a1, m, 64);
        a2 += __shfl_xor(a2, m, 64); a3 += __shfl_xor(a3, m, 64);
      }
      a0 += xcur[0]; a1 += xcur[1]; a2 += xcur[2]; a3 += xcur[3];
      float i_ = 1.f / (1.f + expf(-a0));
      float f_ = 1.f / (1.f + expf(-a1));
      float g_ = tanhf(a2);
      float o_ = 1.f / (1.f + expf(-a3));
      c = f_ * c + i_ * g_;
      float h = o_ * tanhf(c);
      if (li == 0)
        __hip_atomic_store(h_seq + ((size_t)(step + 1) * 4 + batch) * 512 + unit,
                           h, __ATOMIC_RELAXED, __HIP_MEMORY_SCOPE_AGENT);
      // rotate + prefetch xg for step+2 (plain cached loads, off the chain)
#pragma unroll
      for (int g = 0; g < 4; ++g) xcur[g] = xnxt[g];
      if (step + 2 < 256) {
        if (((step + 2) & 63) == 0) {
          const unsigned* fq = xgflag + batch * 4 + ((step + 2) >> 6);
          while (__hip_atomic_load(fq, __ATOMIC_RELAXED, __HIP_MEMORY_SCOPE_AGENT) < 32u) {}
          (void)__hip_atomic_load(fq, __ATOMIC_ACQUIRE, __HIP_MEMORY_SCOPE_AGENT);
        }
        const float* xq = xg + (size_t)(batch * 256 + step + 2) * 2048 + unit;
#pragma unroll
        for (int g = 0; g < 4; ++g) xnxt[g] = xq[g * 512];
      }
    }
  } else if (bid < 576) {
    // ---------------- xg GEMM: xg = x @ W_ih^T + (b_ih+b_hh) -------------
    const int g = bid - 64;
    const int q = g >> 7;              // quarter 0..3 (steps q*64..q*64+63)
    const int b = (g >> 5) & 3;        // batch
    const int col = g & 31;
    const int brow = (b * 4 + q) * 64, bcol = col * 64;
    float4* As4 = (float4*)smem;                 // [64][16]
    float4* Bs4 = (float4*)(smem + 16384);       // [64][16]
    const int tx = t & 15, ty = (t >> 4) & 15;
    const int srow = (t & 255) >> 2, scb = t & 3;
    float acc[4][4] = {};
    for (int kt = 0; kt < 256; kt += 64) {
      if (t < 256) {
#pragma unroll
        for (int u = 0; u < 4; ++u) {
          int cc = scb + 4 * u;
          int gk = kt + cc * 4;
          As4[srow * 16 + (cc ^ (srow & 15))] =
              *(const float4*)(x + (size_t)(brow + srow) * 256 + gk);
          Bs4[srow * 16 + (cc ^ (srow & 15))] =
              *(const float4*)(W_ih + (size_t)(bcol + srow) * 256 + gk);
        }
      }
      __syncthreads();
      if (t < 256) {
#pragma unroll
        for (int d4 = 0; d4 < 16; ++d4) {
          float4 av[4], bv[4];
#pragma unroll
          for (int i = 0; i < 4; ++i)
            av[i] = As4[(ty * 4 + i) * 16 + (d4 ^ ((ty * 4 + i) & 15))];
#pragma unroll
          for (int j = 0; j < 4; ++j)
            bv[j] = Bs4[(tx * 4 + j) * 16 + (d4 ^ ((tx * 4 + j) & 15))];
#pragma unroll
          for (int i = 0; i < 4; ++i)
#pragma unroll
            for (int j = 0; j < 4; ++j)
              acc[i][j] += av[i].x * bv[j].x + av[i].y * bv[j].y +
                           av[i].z * bv[j].z + av[i].w * bv[j].w;
        }
      }
      __syncthreads();
    }
    if (t < 256) {
#pragma unroll
      for (int i = 0; i < 4; ++i) {
        int r = brow + ty * 4 + i;
#pragma unroll
        for (int j = 0; j < 4; ++j) {
          int n = bcol + tx * 4 + j;
          xg[(size_t)r * 2048 + n] = acc[i][j] + b_ih[n] + b_hh[n];
        }
      }
    }
    __syncthreads();                   // all stores issued & drained
    if (t == 0)
      __hip_atomic_fetch_add(xgflag + b * 4 + q, 1u, __ATOMIC_RELEASE,
                             __HIP_MEMORY_SCOPE_AGENT);
  } else {
    // ---------------- key conversion: invn + unit-scaled bf16 ------------
    const int rb = (bid - 576) * 256;
    const int wv = t >> 6, lane = t & 63;
    for (int p = 0; p < 32; ++p) {
      int r = rb + p * 8 + wv;
      if (r < 100000) {
        float2 v = *(const float2*)(keys + (size_t)r * 128 + lane * 2);
        float ss = v.x * v.x + v.y * v.y;
#pragma unroll
        for (int m = 1; m < 64; m <<= 1) ss += __shfl_xor(ss, m, 64);
        float inv = 1.f / fmaxf(sqrtf(ss), 1e-12f);
        if (lane == 0) invn[r] = inv;
        kbf[(size_t)r * 64 + lane] =
            (unsigned)f2bf(v.x * inv) | ((unsigned)f2bf(v.y * inv) << 16);
      }
    }
  }
}

// ---------------- q row-normalize + bf16 pack ------------------------------
__global__ __launch_bounds__(256) void qnorm_k(float* __restrict__ q,
                                               unsigned* __restrict__ qbf) {
  int wv = threadIdx.x >> 6, lane = threadIdx.x & 63;
  int r = blockIdx.x * 4 + wv;
  float2 v = *(float2*)(q + (size_t)r * 128 + lane * 2);
  float ss = v.x * v.x + v.y * v.y;
#pragma unroll
  for (int m = 1; m < 64; m <<= 1) ss += __shfl_xor(ss, m, 64);
  float inv = 1.f / fmaxf(sqrtf(ss), 1e-12f);
  v.x *= inv; v.y *= inv;
  *(float2*)(q + (size_t)r * 128 + lane * 2) = v;
  qbf[(size_t)r * 64 + lane] = (unsigned)f2bf(v.x) | ((unsigned)f2bf(v.y) << 16);
}

// stage one 64x128-bf16 tile: LINEAR LDS dest (global_load_lds), source
// pre-swizzled so readers XOR-deswizzle.
__device__ __forceinline__ void stage_tile(unsigned short* dst,
                                           const unsigned* src,
                                           int baserow, int maxrow,
                                           int w, int l) {
#pragma unroll
  for (int u = 0; u < 4; ++u) {
    int s = u * 256 + w * 64 + l;
    int row = s >> 4, cc = s & 15;
    int gr = baserow + row; gr = gr > maxrow ? maxrow : gr;
    const unsigned* sp = src + (size_t)gr * 64 + ((cc ^ (row & 7)) << 2);
    __builtin_amdgcn_global_load_lds(
        (const __attribute__((address_space(1))) unsigned*)sp,
        (__attribute__((address_space(3))) unsigned*)(dst + (size_t)(u * 256 + w * 64) * 8),
        16, 0, 0);
  }
}

// ---------------- bf16 MFMA sims + per-chunk top-6 candidates --------------
__global__ __launch_bounds__(256, 2) void simsmfma_k(
    const unsigned* __restrict__ qbf, const unsigned* __restrict__ kbf,
    float* __restrict__ pvals, int* __restrict__ pidx) {
  const int qt = blockIdx.x, ch = blockIdx.y;
  const int kbeg = ch * 3125, klim = kbeg + 3125;   // 49 steps of 64
  const int t = threadIdx.x, l = t & 63, w = t >> 6;
  __shared__ alignas(16) unsigned short ks0[8192];
  __shared__ alignas(16) unsigned short ks1[8192];

  stage_tile(ks1, qbf, qt * 64, 1023, w, l);
  __syncthreads();
  bhalf8 afrag[4];
  {
    int row = w * 16 + (l & 15);
#pragma unroll
    for (int db = 0; db < 4; ++db) {
      int cslot = db * 4 + (l >> 4);
      afrag[db] = *(const bhalf8*)&ks1[(size_t)(row * 16 + (cslot ^ (row & 7))) * 8];
    }
  }
  stage_tile(ks0, kbf, kbeg, klim - 1, w, l);
  __syncthreads();

  float tv0[4], tv1[4], tv2[4]; int ti0[4], ti1[4], ti2[4];
#pragma unroll
  for (int r = 0; r < 4; ++r) {
    tv0[r] = tv1[r] = tv2[r] = -INF;
    ti0[r] = ti1[r] = ti2[r] = IMAX;
  }

  for (int s = 0; s < 49; ++s) {
    unsigned short* cur = (s & 1) ? ks1 : ks0;
    unsigned short* nxt = (s & 1) ? ks0 : ks1;
    if (s < 48) stage_tile(nxt, kbf, kbeg + (s + 1) * 64, klim - 1, w, l);
    int k0 = kbeg + s * 64;

    f32x4 ac0 = {0,0,0,0}, ac1 = {0,0,0,0}, ac2 = {0,0,0,0}, ac3 = {0,0,0,0};
    const int r0 = l & 15;
#pragma unroll
    for (int db = 0; db < 4; ++db) {
      int swz = (db * 4 + (l >> 4)) ^ (r0 & 7);
      bhalf8 b0 = *(const bhalf8*)&cur[(size_t)((r0     ) * 16 + swz) * 8];
      bhalf8 b1 = *(const bhalf8*)&cur[(size_t)((r0 + 16) * 16 + swz) * 8];
      bhalf8 b2 = *(const bhalf8*)&cur[(size_t)((r0 + 32) * 16 + swz) * 8];
      bhalf8 b3 = *(const bhalf8*)&cur[(size_t)((r0 + 48) * 16 + swz) * 8];
      ac0 = __builtin_amdgcn_mfma_f32_16x16x32_bf16(afrag[db], b0, ac0, 0, 0, 0);
      ac1 = __builtin_amdgcn_mfma_f32_16x16x32_bf16(afrag[db], b1, ac1, 0, 0, 0);
      ac2 = __builtin_amdgcn_mfma_f32_16x16x32_bf16(afrag[db], b2, ac2, 0, 0, 0);
      ac3 = __builtin_amdgcn_mfma_f32_16x16x32_bf16(afrag[db], b3, ac3, 0, 0, 0);
    }
#pragma unroll
    for (int nt = 0; nt < 4; ++nt) {
      f32x4 a = (nt == 0) ? ac0 : (nt == 1) ? ac1 : (nt == 2) ? ac2 : ac3;
      int gk = k0 + nt * 16 + (l & 15);
      bool ok = gk < klim;
#pragma unroll
      for (int r = 0; r < 4; ++r) {
        float v = ok ? a[r] : -INF;
        ins3b(tv0[r], ti0[r], tv1[r], ti1[r], tv2[r], ti2[r], v, gk);
      }
    }
    __syncthreads();
  }

#pragma unroll
  for (int r = 0; r < 4; ++r) {
    float c0 = tv0[r], c1 = tv1[r], c2 = tv2[r];
    int j0 = ti0[r], j1 = ti1[r], j2 = ti2[r];
    int qrow = qt * 64 + w * 16 + (l >> 4) * 4 + r;
    size_t ob = ((size_t)ch * 1024 + qrow) * 6;
#pragma unroll
    for (int e = 0; e < 6; ++e) {
      float mv = c0; int mi = j0;
#pragma unroll
      for (int m = 1; m < 16; m <<= 1) {
        float o = __shfl_xor(mv, m, 64); int oi = __shfl_xor(mi, m, 64);
        bool tk = (o > mv) || (o == mv && oi < mi);
        mv = tk ? o : mv; mi = tk ? oi : mi;
      }
      if (mi == j0) { c0 = c1; j0 = j1; c1 = c2; j1 = j2; c2 = -INF; j2 = IMAX; }
      if ((l & 15) == 0) { pvals[ob + e] = mv; pidx[ob + e] = mi; }
    }
  }
}

// ---------------- merge chunks + fp32 rescore + attention ------------------
__global__ __launch_bounds__(256) void merge_rescore_k(
    const float* __restrict__ pvals, const int* __restrict__ pidx,
    const float* __restrict__ qf, const float* __restrict__ keys,
    const float* __restrict__ invn, const float* __restrict__ mvals,
    const float* __restrict__ Wa, const float* __restrict__ ba,
    float* __restrict__ mem_pre) {
  int wv = threadIdx.x >> 6, l = threadIdx.x & 63;
  int qr = blockIdx.x * 4 + wv;
  float h0 = -INF, h1 = -INF, h2 = -INF;
  int g0 = IMAX, g1 = IMAX, g2 = IMAX;
#pragma unroll
  for (int e = 0; e < 3; ++e) {
    int c = l * 3 + e;
    size_t base = ((size_t)(c / 6) * 1024 + qr) * 6 + (c % 6);
    ins3b(h0, g0, h1, g1, h2, g2, pvals[base], pidx[base]);
  }
  float sc[8]; int si[8];
#pragma unroll
  for (int e = 0; e < 8; ++e) {
    float mv = h0; int mi = g0;
#pragma unroll
    for (int m = 1; m < 64; m <<= 1) {
      float o = __shfl_xor(mv, m, 64); int oi = __shfl_xor(mi, m, 64);
      bool tk = (o > mv) || (o == mv && oi < mi);
      mv = tk ? o : mv; mi = tk ? oi : mi;
    }
    sc[e] = mv; si[e] = mi;
    if (mi == g0) { h0 = h1; g0 = g1; h1 = h2; g1 = g2; h2 = -INF; g2 = IMAX; }
  }
  int d = l * 2;
  float q0 = qf[(size_t)qr * 128 + d], q1 = qf[(size_t)qr * 128 + d + 1];
  float ex[8];
#pragma unroll
  for (int e = 0; e < 8; ++e) {
    int k = si[e];
    float p = q0 * keys[(size_t)k * 128 + d] + q1 * keys[(size_t)k * 128 + d + 1];
#pragma unroll
    for (int m = 1; m < 64; m <<= 1) p += __shfl_xor(p, m, 64);
    ex[e] = p * invn[k];
  }
  float v0 = -INF, v1 = -INF, v2 = -INF;
  int i0 = IMAX, i1 = IMAX, i2 = IMAX;
#pragma unroll
  for (int e = 0; e < 8; ++e) ins3b(v0, i0, v1, i1, v2, i2, ex[e], si[e]);
  float r00 = mvals[(size_t)i0 * 128 + d], r01 = mvals[(size_t)i0 * 128 + d + 1];
  float r10 = mvals[(size_t)i1 * 128 + d], r11 = mvals[(size_t)i1 * 128 + d + 1];
  float r20 = mvals[(size_t)i2 * 128 + d], r21 = mvals[(size_t)i2 * 128 + d + 1];
  float wa0 = Wa[d], wa1 = Wa[d + 1];
  float p0 = wa0 * r00 + wa1 * r01;
  float p1 = wa0 * r10 + wa1 * r11;
  float p2 = wa0 * r20 + wa1 * r21;
#pragma unroll
  for (int m = 1; m < 64; m <<= 1) {
    p0 += __shfl_xor(p0, m, 64);
    p1 += __shfl_xor(p1, m, 64);
    p2 += __shfl_xor(p2, m, 64);
  }
  float bav = ba[0];
  float l0 = p0 + bav, l1 = p1 + bav, l2 = p2 + bav;
  float mx = fmaxf(l0, fmaxf(l1, l2));
  float e0 = expf(l0 - mx), e1 = expf(l1 - mx), e2 = expf(l2 - mx);
  float s = e0 + e1 + e2;
  float a0 = e0 / s, a1 = e1 / s, a2 = e2 / s;
  mem_pre[(size_t)qr * 128 + d]     = a0 * r00 + a1 * r10 + a2 * r20;
  mem_pre[(size_t)qr * 128 + d + 1] = a0 * r01 + a1 * r11 + a2 * r21;
}

// ---------------------------------------------------------------------------
extern "C" void kernel_launch(void* const* d_in, const int* in_sizes, int n_in,
                              void* d_out, int out_size, void* d_ws, size_t ws_size,
                              hipStream_t stream) {
  (void)in_sizes; (void)n_in; (void)out_size; (void)ws_size;
  const float* x    = (const float*)d_in[0];
  const float* W_ih = (const float*)d_in[1];
  const float* W_hh = (const float*)d_in[2];
  const float* b_ih = (const float*)d_in[3];
  const float* b_hh = (const float*)d_in[4];
  const float* Wq   = (const float*)d_in[5];
  const float* bq   = (const float*)d_in[6];
  const float* Wa   = (const float*)d_in[7];
  const float* ba   = (const float*)d_in[8];
  const float* Wc   = (const float*)d_in[9];
  const float* bc   = (const float*)d_in[10];
  const float* Wo   = (const float*)d_in[11];
  const float* bo   = (const float*)d_in[12];
  const float* keys = (const float*)d_in[13];
  const float* vals = (const float*)d_in[14];

  float* ws      = (float*)d_ws;
  float* xg      = ws + 0;
  float* h_seq   = ws + 2097152;
  float* qbuf    = ws + 2623488;
  float* invn    = ws + 2754560;
  float* mem_pre = ws + 2854560;
  float* mem_cmb = ws + 2985632;
  float* pvals   = ws + 3116704;
  int*   pidx    = (int*)(ws + 3313312);
  unsigned* qbf  = (unsigned*)(ws + 3509920);
  unsigned* kbf  = (unsigned*)(ws + 3575456);
  unsigned* xgflag = (unsigned*)pvals;   // alias: dead until simsmfma writes

  init_k<<<2056, 256, 0, stream>>>(h_seq, xgflag);
  fused_front<<<967, 512, 0, stream>>>(x, W_ih, b_ih, b_hh, W_hh, keys,
                                       xg, h_seq, invn, kbf, xgflag);
  gemm_k<1><<<dim3(16, 2), 256, 0, stream>>>(h_seq, nullptr, Wq, bq, nullptr,
                                             qbuf, 1024, 128, 512);
  qnorm_k<<<256, 256, 0, stream>>>(qbuf, qbf);
  simsmfma_k<<<dim3(16, 32), 256, 0, stream>>>(qbf, kbf, pvals, pidx);
  merge_rescore_k<<<256, 256, 0, stream>>>(pvals, pidx, qbuf, keys, invn, vals,
                                           Wa, ba, mem_pre);
  gemm_k<0><<<dim3(16, 2), 256, 0, stream>>>(mem_pre, nullptr, Wc, bc, nullptr,
                                             mem_cmb, 1024, 128, 128);
  gemm_k<2><<<dim3(16, 4), 256, 0, stream>>>(h_seq, mem_cmb, Wo, bo, nullptr,
                                             (float*)d_out, 1024, 256, 640);
}